// Round 1
// baseline (1445.921 us; speedup 1.0000x reference)
//
#include <hip/hip_runtime.h>

// GCNRegressor: 3x GCNConv(128->128) + mean-pool + 2-layer MLP head.
// Structure: build CSR-by-destination once (atomic-free gathers for all 3
// layers), transform-first GEMM per layer (f32 vector ALU), fused
// bias+ReLU in the aggregation epilogue.

#define HID 128
#define NGR 512

// ---------------- graph prep ----------------

__global__ void k_degree(const int* __restrict__ col, int* __restrict__ cnt, int E) {
    int e = blockIdx.x * blockDim.x + threadIdx.x;
    if (e < E) atomicAdd(&cnt[col[e]], 1);
}

__global__ void k_dis(const int* __restrict__ cnt, float* __restrict__ dis, int N) {
    int n = blockIdx.x * blockDim.x + threadIdx.x;
    if (n < N) dis[n] = rsqrtf((float)(cnt[n] + 1));   // +1 self-loop; deg>=1 always
}

// single-block exclusive scan of cnt -> rowptr; zeroes cnt for reuse as cursor.
__global__ __launch_bounds__(1024) void k_scan(int* __restrict__ cnt, int* __restrict__ rowptr, int N) {
    __shared__ int wsum[16];
    const int lane = threadIdx.x & 63;
    const int wid  = threadIdx.x >> 6;
    int carry = 0;
    for (int base = 0; base < N; base += 4096) {
        int i0 = base + threadIdx.x * 4;
        int v[4];
        #pragma unroll
        for (int j = 0; j < 4; j++) {
            int idx = i0 + j;
            v[j] = (idx < N) ? cnt[idx] : 0;
            if (idx < N) cnt[idx] = 0;
        }
        int tsum = v[0] + v[1] + v[2] + v[3];
        int sc = tsum;
        #pragma unroll
        for (int off = 1; off < 64; off <<= 1) {
            int t = __shfl_up(sc, off);
            if (lane >= off) sc += t;
        }
        if (lane == 63) wsum[wid] = sc;
        __syncthreads();
        int woff = 0, tot = 0;
        #pragma unroll
        for (int w = 0; w < 16; w++) {
            if (w < wid) woff += wsum[w];
            tot += wsum[w];
        }
        int excl = carry + woff + sc - tsum;
        #pragma unroll
        for (int j = 0; j < 4; j++) {
            int idx = i0 + j;
            if (idx < N) rowptr[idx] = excl;
            excl += v[j];
        }
        carry += tot;
        __syncthreads();
    }
    if (threadIdx.x == 0) rowptr[N] = carry;
}

__global__ void k_fill(const int* __restrict__ row, const int* __restrict__ col,
                       const float* __restrict__ dis, const int* __restrict__ rowptr,
                       int* __restrict__ cur, int* __restrict__ csr_src,
                       float* __restrict__ csr_w, int E) {
    int e = blockIdx.x * blockDim.x + threadIdx.x;
    if (e < E) {
        int d = col[e], s = row[e];
        int pos = rowptr[d] + atomicAdd(&cur[d], 1);
        csr_src[pos] = s;
        csr_w[pos]   = dis[s] * dis[d];
    }
}

// ---------------- GEMM: C[N,128] = A[N,128] @ W[128,128] ----------------
// 64x64 block tile, KC=16, 4x4 per thread, f32.

#define BM 64
#define BN 64
#define KC 16

__global__ __launch_bounds__(256) void k_gemm(const float* __restrict__ A,
                                              const float* __restrict__ W,
                                              float* __restrict__ C, int N) {
    __shared__ float As[KC][BM];   // k-major (transposed)
    __shared__ float Bs[KC][BN];
    const int row0 = blockIdx.x * BM;
    const int col0 = blockIdx.y * BN;
    const int t  = threadIdx.x;
    const int tc = t & 15;   // col group (4 cols)
    const int tr = t >> 4;   // row group (4 rows)

    float acc[4][4] = {};

    for (int k0 = 0; k0 < HID; k0 += KC) {
        // stage A tile transposed: thread loads float4 of one row
        {
            int r  = t >> 2;
            int kk = (t & 3) * 4;
            int gr = row0 + r;
            float4 v = make_float4(0.f, 0.f, 0.f, 0.f);
            if (gr < N) v = *(const float4*)(A + (size_t)gr * HID + k0 + kk);
            As[kk + 0][r] = v.x; As[kk + 1][r] = v.y;
            As[kk + 2][r] = v.z; As[kk + 3][r] = v.w;
        }
        // stage W tile
        {
            int kk = t >> 4;
            int c4 = (t & 15) * 4;
            *(float4*)&Bs[kk][c4] = *(const float4*)(W + (size_t)(k0 + kk) * HID + col0 + c4);
        }
        __syncthreads();
        #pragma unroll
        for (int k = 0; k < KC; k++) {
            float4 a = *(const float4*)&As[k][tr * 4];
            float4 b = *(const float4*)&Bs[k][tc * 4];
            float av[4] = {a.x, a.y, a.z, a.w};
            float bv[4] = {b.x, b.y, b.z, b.w};
            #pragma unroll
            for (int i = 0; i < 4; i++)
                #pragma unroll
                for (int j = 0; j < 4; j++)
                    acc[i][j] = fmaf(av[i], bv[j], acc[i][j]);
        }
        __syncthreads();
    }
    #pragma unroll
    for (int i = 0; i < 4; i++) {
        int gr = row0 + tr * 4 + i;
        if (gr < N) {
            float4 o = make_float4(acc[i][0], acc[i][1], acc[i][2], acc[i][3]);
            *(float4*)(C + (size_t)gr * HID + col0 + tc * 4) = o;
        }
    }
}

// ---------------- aggregation: out[n] = relu(sum_e w_e*T[src_e] + dis[n]^2*T[n] + b) ----------------
// one wave64 per node; lane owns float2 of the 128-wide row.

__global__ __launch_bounds__(256) void k_agg(const float* __restrict__ T,
                                             const float* __restrict__ dis,
                                             const int* __restrict__ rowptr,
                                             const int* __restrict__ csr_src,
                                             const float* __restrict__ csr_w,
                                             const float* __restrict__ bias,
                                             float* __restrict__ out, int N) {
    const int wid  = threadIdx.x >> 6;
    const int lane = threadIdx.x & 63;
    const int n = blockIdx.x * 4 + wid;
    if (n >= N) return;

    float d = dis[n];
    float sl = d * d;
    float2 tn = ((const float2*)(T + (size_t)n * HID))[lane];
    float accx = sl * tn.x, accy = sl * tn.y;

    int e  = rowptr[n];
    int e1 = rowptr[n + 1];
    for (; e + 3 < e1; e += 4) {
        int   s0 = csr_src[e],     s1 = csr_src[e + 1];
        int   s2 = csr_src[e + 2], s3 = csr_src[e + 3];
        float w0 = csr_w[e],       w1 = csr_w[e + 1];
        float w2 = csr_w[e + 2],   w3 = csr_w[e + 3];
        float2 v0 = ((const float2*)(T + (size_t)s0 * HID))[lane];
        float2 v1 = ((const float2*)(T + (size_t)s1 * HID))[lane];
        float2 v2 = ((const float2*)(T + (size_t)s2 * HID))[lane];
        float2 v3 = ((const float2*)(T + (size_t)s3 * HID))[lane];
        accx = fmaf(w0, v0.x, accx); accy = fmaf(w0, v0.y, accy);
        accx = fmaf(w1, v1.x, accx); accy = fmaf(w1, v1.y, accy);
        accx = fmaf(w2, v2.x, accx); accy = fmaf(w2, v2.y, accy);
        accx = fmaf(w3, v3.x, accx); accy = fmaf(w3, v3.y, accy);
    }
    for (; e < e1; e++) {
        int   s = csr_src[e];
        float w = csr_w[e];
        float2 v = ((const float2*)(T + (size_t)s * HID))[lane];
        accx = fmaf(w, v.x, accx); accy = fmaf(w, v.y, accy);
    }
    float2 b = ((const float2*)bias)[lane];
    float2 o;
    o.x = fmaxf(accx + b.x, 0.f);
    o.y = fmaxf(accy + b.y, 0.f);
    ((float2*)(out + (size_t)n * HID))[lane] = o;
}

// ---------------- pooling ----------------

__global__ void k_gstart(const int* __restrict__ batch, int* __restrict__ gstart, int N) {
    int g = blockIdx.x * blockDim.x + threadIdx.x;
    if (g > NGR) return;
    int lo = 0, hi = N;
    while (lo < hi) {
        int mid = (lo + hi) >> 1;
        if (batch[mid] < g) lo = mid + 1; else hi = mid;
    }
    gstart[g] = lo;
}

__global__ __launch_bounds__(128) void k_pool(const float* __restrict__ h,
                                              const int* __restrict__ gstart,
                                              float* __restrict__ g) {
    int gr = blockIdx.x;
    int f  = threadIdx.x;
    int s = gstart[gr], e = gstart[gr + 1];
    float acc = 0.f;
    for (int r = s; r < e; r++) acc += h[(size_t)r * HID + f];
    g[gr * HID + f] = acc / fmaxf((float)(e - s), 1.f);
}

// ---------------- MLP head ----------------

__global__ __launch_bounds__(128) void k_mlp(const float* __restrict__ g,
                                             const float* __restrict__ Wm0,
                                             const float* __restrict__ bm0,
                                             const float* __restrict__ Wm1,
                                             const float* __restrict__ bm1,
                                             float* __restrict__ out) {
    __shared__ float gl[HID];
    __shared__ float red[HID];
    int gr = blockIdx.x, j = threadIdx.x;
    gl[j] = g[gr * HID + j];
    __syncthreads();
    float acc = bm0[j];
    for (int k = 0; k < HID; k++) acc = fmaf(gl[k], Wm0[k * HID + j], acc);
    acc = fmaxf(acc, 0.f);
    red[j] = acc * Wm1[j];
    __syncthreads();
    for (int off = 64; off > 0; off >>= 1) {
        if (j < off) red[j] += red[j + off];
        __syncthreads();
    }
    if (j == 0) out[gr] = red[0] + bm1[0];
}

// ---------------- launch ----------------

extern "C" void kernel_launch(void* const* d_in, const int* in_sizes, int n_in,
                              void* d_out, int out_size, void* d_ws, size_t ws_size,
                              hipStream_t stream) {
    const float* x     = (const float*)d_in[0];
    const int*   ei    = (const int*)d_in[1];
    const int*   batch = (const int*)d_in[3];
    const float* W0 = (const float*)d_in[4],  *b0 = (const float*)d_in[5];
    const float* W1 = (const float*)d_in[6],  *b1 = (const float*)d_in[7];
    const float* W2 = (const float*)d_in[8],  *b2 = (const float*)d_in[9];
    const float* Wm0 = (const float*)d_in[10], *bm0 = (const float*)d_in[11];
    const float* Wm1 = (const float*)d_in[12], *bm1 = (const float*)d_in[13];

    const int N = in_sizes[0] / HID;
    const int E = in_sizes[1] / 2;
    const int* row  = ei;
    const int* colI = ei + E;

    // workspace carve (~181 MB)
    char* w = (char*)d_ws;
    auto carve = [&](size_t bytes) {
        void* p = (void*)w;
        w += (bytes + 255) & ~(size_t)255;
        return p;
    };
    int*   cnt     = (int*)  carve((size_t)N * 4);
    float* dis     = (float*)carve((size_t)N * 4);
    int*   rowptr  = (int*)  carve((size_t)(N + 1) * 4);
    int*   csr_src = (int*)  carve((size_t)E * 4);
    float* csr_w   = (float*)carve((size_t)E * 4);
    float* bufT    = (float*)carve((size_t)N * HID * 4);
    float* bufA    = (float*)carve((size_t)N * HID * 4);
    float* bufB    = (float*)carve((size_t)N * HID * 4);
    float* gsum    = (float*)carve((size_t)NGR * HID * 4);
    int*   gstart  = (int*)  carve((size_t)(NGR + 1) * 4);

    hipMemsetAsync(cnt, 0, (size_t)N * 4, stream);
    k_degree<<<(E + 255) / 256, 256, 0, stream>>>(colI, cnt, E);
    k_dis<<<(N + 255) / 256, 256, 0, stream>>>(cnt, dis, N);
    k_scan<<<1, 1024, 0, stream>>>(cnt, rowptr, N);          // also zeroes cnt -> cursor
    k_fill<<<(E + 255) / 256, 256, 0, stream>>>(row, colI, dis, rowptr, cnt, csr_src, csr_w, E);

    dim3 gg((N + BM - 1) / BM, HID / BN);
    dim3 ga((N + 3) / 4);

    k_gemm<<<gg, 256, 0, stream>>>(x,    W0, bufT, N);
    k_agg <<<ga, 256, 0, stream>>>(bufT, dis, rowptr, csr_src, csr_w, b0, bufA, N);
    k_gemm<<<gg, 256, 0, stream>>>(bufA, W1, bufT, N);
    k_agg <<<ga, 256, 0, stream>>>(bufT, dis, rowptr, csr_src, csr_w, b1, bufB, N);
    k_gemm<<<gg, 256, 0, stream>>>(bufB, W2, bufT, N);
    k_agg <<<ga, 256, 0, stream>>>(bufT, dis, rowptr, csr_src, csr_w, b2, bufA, N);

    k_gstart<<<3, 256, 0, stream>>>(batch, gstart, N);
    k_pool<<<NGR, 128, 0, stream>>>(bufA, gstart, gsum);
    k_mlp<<<NGR, 128, 0, stream>>>(gsum, Wm0, bm0, Wm1, bm1, (float*)d_out);
}

// Round 2
// 1172.884 us; speedup vs baseline: 1.2328x; 1.2328x over previous
//
#include <hip/hip_runtime.h>

// GCNRegressor: 3x GCNConv(128->128) + mean-pool + 2-layer MLP head.
// CSR-by-destination built via two-level bucket sort (dense writes, no
// write-amplified scatter); transform-first f32 GEMM; fused bias+ReLU in
// the atomic-free gather aggregation.

#define HID 128
#define NGR 512
#define NB_SHIFT 9
#define NB_W 512            // dests per bucket
#define EPB 4096            // edges per k_scatter block

// ---------------- graph prep: bucket sort by destination ----------------

// Global bucket histogram (LDS-aggregated). nb <= 256 (N <= 131072).
__global__ __launch_bounds__(256) void k_hist(const int* __restrict__ col,
                                              int* __restrict__ ghist, int E, int nb) {
    __shared__ int h[256];
    h[threadIdx.x] = 0;
    __syncthreads();
    for (int e = blockIdx.x * 256 + threadIdx.x; e < E; e += gridDim.x * 256)
        atomicAdd(&h[col[e] >> NB_SHIFT], 1);
    __syncthreads();
    int t = threadIdx.x;
    if (t < nb && h[t]) atomicAdd(&ghist[t], h[t]);
}

// Single block: exclusive scan of ghist -> bbase[0..nb]; also rowptr[N] = E.
// Requires nb < 256 (here nb = ceil(100000/512) = 196).
__global__ __launch_bounds__(256) void k_bscan(const int* __restrict__ ghist,
                                               int* __restrict__ bbase,
                                               int* __restrict__ rowptr,
                                               int N, int E, int nb) {
    __shared__ int wsum[4];
    int t = threadIdx.x, lane = t & 63, wid = t >> 6;
    int v = (t < nb) ? ghist[t] : 0;
    int sc = v;
    #pragma unroll
    for (int off = 1; off < 64; off <<= 1) {
        int u = __shfl_up(sc, off);
        if (lane >= off) sc += u;
    }
    if (lane == 63) wsum[wid] = sc;
    __syncthreads();
    int offs = 0;
    for (int w = 0; w < wid; w++) offs += wsum[w];
    int excl = offs + sc - v;
    if (t <= nb) bbase[t] = excl;       // bbase[nb] == E (ghist[j>=nb]==0)
    if (t == 0) rowptr[N] = E;
}

// Coarse scatter into bucket regions. Block-aggregated ticketing: one global
// atomic per (block,bucket); ranks via LDS atomics. Appends are in ticket
// order -> dense, full-line writebacks.
__global__ __launch_bounds__(256) void k_scatter(const int* __restrict__ row,
                                                 const int* __restrict__ col,
                                                 const int* __restrict__ bbase,
                                                 int* __restrict__ bcur,
                                                 uint2* __restrict__ sorted, int E) {
    __shared__ int hist[256];
    __shared__ int cur[256];
    int t = threadIdx.x;
    hist[t] = 0;
    __syncthreads();
    int base = blockIdx.x * EPB;
    #pragma unroll
    for (int i = 0; i < EPB / 256; i++) {
        int e = base + i * 256 + t;
        if (e < E) atomicAdd(&hist[col[e] >> NB_SHIFT], 1);
    }
    __syncthreads();
    if (hist[t] > 0) cur[t] = atomicAdd(&bcur[t], hist[t]);
    __syncthreads();
    #pragma unroll
    for (int i = 0; i < EPB / 256; i++) {
        int e = base + i * 256 + t;
        if (e < E) {
            int d = col[e], b = d >> NB_SHIFT;
            int p = atomicAdd(&cur[b], 1);
            sorted[bbase[b] + p] = make_uint2((unsigned)row[e], (unsigned)d);
        }
    }
}

// One block per bucket: LDS histogram over the bucket's 512 dests -> scan ->
// rowptr + dis (= rsqrt(deg+1)) + in-bucket sorted order (L2-resident window).
__global__ __launch_bounds__(256) void k_build(const uint2* __restrict__ sorted,
                                               const int* __restrict__ bbase,
                                               uint2* __restrict__ sorted2,
                                               int* __restrict__ rowptr,
                                               float* __restrict__ dis, int N) {
    __shared__ int cnt[NB_W];
    __shared__ int excl[NB_W];
    __shared__ int wsum[4];
    int b = blockIdx.x, t = threadIdx.x;
    cnt[t] = 0; cnt[t + 256] = 0;
    __syncthreads();
    int s0 = bbase[b], s1 = bbase[b + 1];
    for (int p = s0 + t; p < s1; p += 256) {
        uint2 sd = sorted[p];
        atomicAdd(&cnt[sd.y & (NB_W - 1)], 1);
    }
    __syncthreads();
    int c0 = cnt[2 * t], c1 = cnt[2 * t + 1];
    int v = c0 + c1, lane = t & 63, wid = t >> 6;
    int sc = v;
    #pragma unroll
    for (int off = 1; off < 64; off <<= 1) {
        int u = __shfl_up(sc, off);
        if (lane >= off) sc += u;
    }
    if (lane == 63) wsum[wid] = sc;
    __syncthreads();
    int offs = 0;
    for (int w = 0; w < wid; w++) offs += wsum[w];
    int e0 = offs + sc - v;
    excl[2 * t] = e0;
    excl[2 * t + 1] = e0 + c0;
    int dbase = b << NB_SHIFT;
    int d0 = dbase + 2 * t, d1 = d0 + 1;
    if (d0 < N) { rowptr[d0] = s0 + e0;      dis[d0] = rsqrtf((float)(c0 + 1)); }
    if (d1 < N) { rowptr[d1] = s0 + e0 + c0; dis[d1] = rsqrtf((float)(c1 + 1)); }
    __syncthreads();
    for (int p = s0 + t; p < s1; p += 256) {
        uint2 sd = sorted[p];
        int q = atomicAdd(&excl[sd.y & (NB_W - 1)], 1);
        sorted2[s0 + q] = sd;
    }
}

// Coalesced pass: csr_src + csr_w = dis[s]*dis[d] (dis is 400 KB, L2-hot).
__global__ void k_weight(const uint2* __restrict__ sorted2, const float* __restrict__ dis,
                         int* __restrict__ csr_src, float* __restrict__ csr_w, int E) {
    int p = blockIdx.x * blockDim.x + threadIdx.x;
    if (p < E) {
        uint2 sd = sorted2[p];
        csr_src[p] = (int)sd.x;
        csr_w[p]   = dis[sd.x] * dis[sd.y];
    }
}

// ---------------- GEMM: C[N,128] = A[N,128] @ W[128,128] ----------------

#define BM 64
#define BN 64
#define KC 16

__global__ __launch_bounds__(256) void k_gemm(const float* __restrict__ A,
                                              const float* __restrict__ W,
                                              float* __restrict__ C, int N) {
    __shared__ float As[KC][BM];
    __shared__ float Bs[KC][BN];
    const int row0 = blockIdx.x * BM;
    const int col0 = blockIdx.y * BN;
    const int t  = threadIdx.x;
    const int tc = t & 15;
    const int tr = t >> 4;

    float acc[4][4] = {};

    for (int k0 = 0; k0 < HID; k0 += KC) {
        {
            int r  = t >> 2;
            int kk = (t & 3) * 4;
            int gr = row0 + r;
            float4 v = make_float4(0.f, 0.f, 0.f, 0.f);
            if (gr < N) v = *(const float4*)(A + (size_t)gr * HID + k0 + kk);
            As[kk + 0][r] = v.x; As[kk + 1][r] = v.y;
            As[kk + 2][r] = v.z; As[kk + 3][r] = v.w;
        }
        {
            int kk = t >> 4;
            int c4 = (t & 15) * 4;
            *(float4*)&Bs[kk][c4] = *(const float4*)(W + (size_t)(k0 + kk) * HID + col0 + c4);
        }
        __syncthreads();
        #pragma unroll
        for (int k = 0; k < KC; k++) {
            float4 a = *(const float4*)&As[k][tr * 4];
            float4 b = *(const float4*)&Bs[k][tc * 4];
            float av[4] = {a.x, a.y, a.z, a.w};
            float bv[4] = {b.x, b.y, b.z, b.w};
            #pragma unroll
            for (int i = 0; i < 4; i++)
                #pragma unroll
                for (int j = 0; j < 4; j++)
                    acc[i][j] = fmaf(av[i], bv[j], acc[i][j]);
        }
        __syncthreads();
    }
    #pragma unroll
    for (int i = 0; i < 4; i++) {
        int gr = row0 + tr * 4 + i;
        if (gr < N) {
            float4 o = make_float4(acc[i][0], acc[i][1], acc[i][2], acc[i][3]);
            *(float4*)(C + (size_t)gr * HID + col0 + tc * 4) = o;
        }
    }
}

// ---------------- aggregation ----------------
// out[n] = relu(sum_e w_e*T[src_e] + dis[n]^2*T[n] + b); one wave64 per node.

__global__ __launch_bounds__(256) void k_agg(const float* __restrict__ T,
                                             const float* __restrict__ dis,
                                             const int* __restrict__ rowptr,
                                             const int* __restrict__ csr_src,
                                             const float* __restrict__ csr_w,
                                             const float* __restrict__ bias,
                                             float* __restrict__ out, int N) {
    const int wid  = threadIdx.x >> 6;
    const int lane = threadIdx.x & 63;
    const int n = blockIdx.x * 4 + wid;
    if (n >= N) return;

    float d = dis[n];
    float sl = d * d;
    float2 tn = ((const float2*)(T + (size_t)n * HID))[lane];
    float accx = sl * tn.x, accy = sl * tn.y;

    int e  = rowptr[n];
    int e1 = rowptr[n + 1];
    for (; e + 3 < e1; e += 4) {
        int   s0 = csr_src[e],     s1 = csr_src[e + 1];
        int   s2 = csr_src[e + 2], s3 = csr_src[e + 3];
        float w0 = csr_w[e],       w1 = csr_w[e + 1];
        float w2 = csr_w[e + 2],   w3 = csr_w[e + 3];
        float2 v0 = ((const float2*)(T + (size_t)s0 * HID))[lane];
        float2 v1 = ((const float2*)(T + (size_t)s1 * HID))[lane];
        float2 v2 = ((const float2*)(T + (size_t)s2 * HID))[lane];
        float2 v3 = ((const float2*)(T + (size_t)s3 * HID))[lane];
        accx = fmaf(w0, v0.x, accx); accy = fmaf(w0, v0.y, accy);
        accx = fmaf(w1, v1.x, accx); accy = fmaf(w1, v1.y, accy);
        accx = fmaf(w2, v2.x, accx); accy = fmaf(w2, v2.y, accy);
        accx = fmaf(w3, v3.x, accx); accy = fmaf(w3, v3.y, accy);
    }
    for (; e < e1; e++) {
        int   s = csr_src[e];
        float w = csr_w[e];
        float2 v = ((const float2*)(T + (size_t)s * HID))[lane];
        accx = fmaf(w, v.x, accx); accy = fmaf(w, v.y, accy);
    }
    float2 b = ((const float2*)bias)[lane];
    float2 o;
    o.x = fmaxf(accx + b.x, 0.f);
    o.y = fmaxf(accy + b.y, 0.f);
    ((float2*)(out + (size_t)n * HID))[lane] = o;
}

// ---------------- pooling ----------------

__global__ void k_gstart(const int* __restrict__ batch, int* __restrict__ gstart, int N) {
    int g = blockIdx.x * blockDim.x + threadIdx.x;
    if (g > NGR) return;
    int lo = 0, hi = N;
    while (lo < hi) {
        int mid = (lo + hi) >> 1;
        if (batch[mid] < g) lo = mid + 1; else hi = mid;
    }
    gstart[g] = lo;
}

__global__ __launch_bounds__(128) void k_pool(const float* __restrict__ h,
                                              const int* __restrict__ gstart,
                                              float* __restrict__ g) {
    int gr = blockIdx.x;
    int f  = threadIdx.x;
    int s = gstart[gr], e = gstart[gr + 1];
    float acc = 0.f;
    for (int r = s; r < e; r++) acc += h[(size_t)r * HID + f];
    g[gr * HID + f] = acc / fmaxf((float)(e - s), 1.f);
}

// ---------------- MLP head ----------------

__global__ __launch_bounds__(128) void k_mlp(const float* __restrict__ g,
                                             const float* __restrict__ Wm0,
                                             const float* __restrict__ bm0,
                                             const float* __restrict__ Wm1,
                                             const float* __restrict__ bm1,
                                             float* __restrict__ out) {
    __shared__ float gl[HID];
    __shared__ float red[HID];
    int gr = blockIdx.x, j = threadIdx.x;
    gl[j] = g[gr * HID + j];
    __syncthreads();
    float acc = bm0[j];
    for (int k = 0; k < HID; k++) acc = fmaf(gl[k], Wm0[k * HID + j], acc);
    acc = fmaxf(acc, 0.f);
    red[j] = acc * Wm1[j];
    __syncthreads();
    for (int off = 64; off > 0; off >>= 1) {
        if (j < off) red[j] += red[j + off];
        __syncthreads();
    }
    if (j == 0) out[gr] = red[0] + bm1[0];
}

// ---------------- launch ----------------

extern "C" void kernel_launch(void* const* d_in, const int* in_sizes, int n_in,
                              void* d_out, int out_size, void* d_ws, size_t ws_size,
                              hipStream_t stream) {
    const float* x     = (const float*)d_in[0];
    const int*   ei    = (const int*)d_in[1];
    const int*   batch = (const int*)d_in[3];
    const float* W0 = (const float*)d_in[4],  *b0 = (const float*)d_in[5];
    const float* W1 = (const float*)d_in[6],  *b1 = (const float*)d_in[7];
    const float* W2 = (const float*)d_in[8],  *b2 = (const float*)d_in[9];
    const float* Wm0 = (const float*)d_in[10], *bm0 = (const float*)d_in[11];
    const float* Wm1 = (const float*)d_in[12], *bm1 = (const float*)d_in[13];

    const int N = in_sizes[0] / HID;
    const int E = in_sizes[1] / 2;
    const int nb = (N + NB_W - 1) >> NB_SHIFT;   // 196 for N=100000
    const int* row  = ei;
    const int* colI = ei + E;

    char* w = (char*)d_ws;
    auto carve = [&](size_t bytes) {
        void* p = (void*)w;
        w += (bytes + 255) & ~(size_t)255;
        return p;
    };
    int*   ibuf    = (int*)  carve(512 * 4);                 // ghist(256) + bcur(256)
    int*   bbase   = (int*)  carve(257 * 4);
    float* dis     = (float*)carve((size_t)N * 4);
    int*   rowptr  = (int*)  carve((size_t)(N + 1) * 4);
    uint2* sorted  = (uint2*)carve((size_t)E * 8);
    uint2* sorted2 = (uint2*)carve((size_t)E * 8);
    int*   csr_src = (int*)  carve((size_t)E * 4);
    float* csr_w   = (float*)carve((size_t)E * 4);
    float* bufT    = (float*)carve((size_t)N * HID * 4);
    float* bufA    = (float*)carve((size_t)N * HID * 4);
    float* bufB    = (float*)carve((size_t)N * HID * 4);
    float* gsum    = (float*)carve((size_t)NGR * HID * 4);
    int*   gstart  = (int*)  carve((size_t)(NGR + 1) * 4);

    int* ghist = ibuf;
    int* bcur  = ibuf + 256;

    hipMemsetAsync(ibuf, 0, 512 * 4, stream);
    k_hist   <<<512, 256, 0, stream>>>(colI, ghist, E, nb);
    k_bscan  <<<1, 256, 0, stream>>>(ghist, bbase, rowptr, N, E, nb);
    k_scatter<<<(E + EPB - 1) / EPB, 256, 0, stream>>>(row, colI, bbase, bcur, sorted, E);
    k_build  <<<nb, 256, 0, stream>>>(sorted, bbase, sorted2, rowptr, dis, N);
    k_weight <<<(E + 255) / 256, 256, 0, stream>>>(sorted2, dis, csr_src, csr_w, E);

    dim3 gg((N + BM - 1) / BM, HID / BN);
    dim3 ga((N + 3) / 4);

    k_gemm<<<gg, 256, 0, stream>>>(x,    W0, bufT, N);
    k_agg <<<ga, 256, 0, stream>>>(bufT, dis, rowptr, csr_src, csr_w, b0, bufA, N);
    k_gemm<<<gg, 256, 0, stream>>>(bufA, W1, bufT, N);
    k_agg <<<ga, 256, 0, stream>>>(bufT, dis, rowptr, csr_src, csr_w, b1, bufB, N);
    k_gemm<<<gg, 256, 0, stream>>>(bufB, W2, bufT, N);
    k_agg <<<ga, 256, 0, stream>>>(bufT, dis, rowptr, csr_src, csr_w, b2, bufA, N);

    k_gstart<<<3, 256, 0, stream>>>(batch, gstart, N);
    k_pool<<<NGR, 128, 0, stream>>>(bufA, gstart, gsum);
    k_mlp<<<NGR, 128, 0, stream>>>(gsum, Wm0, bm0, Wm1, bm1, (float*)d_out);
}

// Round 3
// 839.411 us; speedup vs baseline: 1.7225x; 1.3973x over previous
//
#include <hip/hip_runtime.h>
#include <hip/hip_fp16.h>

// GCNRegressor: 3x GCNConv(128->128) + mean-pool + 2-layer MLP head.
// CSR-by-destination via two-level bucket sort; transform-first f32 GEMM
// writing T in fp16 (halves the random-gather bytes); gather aggregation
// reads 4 edges per wave-load (16 lanes x float4 = one 256 B fp16 row),
// f32 accumulate, quarter-wave partials combined by shfl_xor.

#define HID 128
#define NGR 512
#define NB_SHIFT 9
#define NB_W 512
#define EPB 4096

// ---------------- graph prep: bucket sort by destination ----------------

__global__ __launch_bounds__(256) void k_hist(const int* __restrict__ col,
                                              int* __restrict__ ghist, int E, int nb) {
    __shared__ int h[256];
    h[threadIdx.x] = 0;
    __syncthreads();
    for (int e = blockIdx.x * 256 + threadIdx.x; e < E; e += gridDim.x * 256)
        atomicAdd(&h[col[e] >> NB_SHIFT], 1);
    __syncthreads();
    int t = threadIdx.x;
    if (t < nb && h[t]) atomicAdd(&ghist[t], h[t]);
}

__global__ __launch_bounds__(256) void k_bscan(const int* __restrict__ ghist,
                                               int* __restrict__ bbase,
                                               int* __restrict__ rowptr,
                                               int N, int E, int nb) {
    __shared__ int wsum[4];
    int t = threadIdx.x, lane = t & 63, wid = t >> 6;
    int v = (t < nb) ? ghist[t] : 0;
    int sc = v;
    #pragma unroll
    for (int off = 1; off < 64; off <<= 1) {
        int u = __shfl_up(sc, off);
        if (lane >= off) sc += u;
    }
    if (lane == 63) wsum[wid] = sc;
    __syncthreads();
    int offs = 0;
    for (int w = 0; w < wid; w++) offs += wsum[w];
    int excl = offs + sc - v;
    if (t <= nb) bbase[t] = excl;
    if (t == 0) rowptr[N] = E;
}

__global__ __launch_bounds__(256) void k_scatter(const int* __restrict__ row,
                                                 const int* __restrict__ col,
                                                 const int* __restrict__ bbase,
                                                 int* __restrict__ bcur,
                                                 uint2* __restrict__ sorted, int E) {
    __shared__ int hist[256];
    __shared__ int cur[256];
    int t = threadIdx.x;
    hist[t] = 0;
    __syncthreads();
    int base = blockIdx.x * EPB;
    #pragma unroll
    for (int i = 0; i < EPB / 256; i++) {
        int e = base + i * 256 + t;
        if (e < E) atomicAdd(&hist[col[e] >> NB_SHIFT], 1);
    }
    __syncthreads();
    if (hist[t] > 0) cur[t] = atomicAdd(&bcur[t], hist[t]);
    __syncthreads();
    #pragma unroll
    for (int i = 0; i < EPB / 256; i++) {
        int e = base + i * 256 + t;
        if (e < E) {
            int d = col[e], b = d >> NB_SHIFT;
            int p = atomicAdd(&cur[b], 1);
            sorted[bbase[b] + p] = make_uint2((unsigned)row[e], (unsigned)d);
        }
    }
}

__global__ __launch_bounds__(256) void k_build(const uint2* __restrict__ sorted,
                                               const int* __restrict__ bbase,
                                               uint2* __restrict__ sorted2,
                                               int* __restrict__ rowptr,
                                               float* __restrict__ dis, int N) {
    __shared__ int cnt[NB_W];
    __shared__ int excl[NB_W];
    __shared__ int wsum[4];
    int b = blockIdx.x, t = threadIdx.x;
    cnt[t] = 0; cnt[t + 256] = 0;
    __syncthreads();
    int s0 = bbase[b], s1 = bbase[b + 1];
    for (int p = s0 + t; p < s1; p += 256) {
        uint2 sd = sorted[p];
        atomicAdd(&cnt[sd.y & (NB_W - 1)], 1);
    }
    __syncthreads();
    int c0 = cnt[2 * t], c1 = cnt[2 * t + 1];
    int v = c0 + c1, lane = t & 63, wid = t >> 6;
    int sc = v;
    #pragma unroll
    for (int off = 1; off < 64; off <<= 1) {
        int u = __shfl_up(sc, off);
        if (lane >= off) sc += u;
    }
    if (lane == 63) wsum[wid] = sc;
    __syncthreads();
    int offs = 0;
    for (int w = 0; w < wid; w++) offs += wsum[w];
    int e0 = offs + sc - v;
    excl[2 * t] = e0;
    excl[2 * t + 1] = e0 + c0;
    int dbase = b << NB_SHIFT;
    int d0 = dbase + 2 * t, d1 = d0 + 1;
    if (d0 < N) { rowptr[d0] = s0 + e0;      dis[d0] = rsqrtf((float)(c0 + 1)); }
    if (d1 < N) { rowptr[d1] = s0 + e0 + c0; dis[d1] = rsqrtf((float)(c1 + 1)); }
    __syncthreads();
    for (int p = s0 + t; p < s1; p += 256) {
        uint2 sd = sorted[p];
        int q = atomicAdd(&excl[sd.y & (NB_W - 1)], 1);
        sorted2[s0 + q] = sd;
    }
}

__global__ void k_weight(const uint2* __restrict__ sorted2, const float* __restrict__ dis,
                         int* __restrict__ csr_src, float* __restrict__ csr_w, int E) {
    int p = blockIdx.x * blockDim.x + threadIdx.x;
    if (p < E) {
        uint2 sd = sorted2[p];
        csr_src[p] = (int)sd.x;
        csr_w[p]   = dis[sd.x] * dis[sd.y];
    }
}

// ---------------- GEMM: T[N,128] (fp16) = A[N,128] @ W[128,128] (f32 math) ----

#define BM 64
#define BN 64
#define KC 16

__global__ __launch_bounds__(256) void k_gemm(const float* __restrict__ A,
                                              const float* __restrict__ W,
                                              __half* __restrict__ C, int N) {
    __shared__ float As[KC][BM];
    __shared__ float Bs[KC][BN];
    const int row0 = blockIdx.x * BM;
    const int col0 = blockIdx.y * BN;
    const int t  = threadIdx.x;
    const int tc = t & 15;
    const int tr = t >> 4;

    float acc[4][4] = {};

    for (int k0 = 0; k0 < HID; k0 += KC) {
        {
            int r  = t >> 2;
            int kk = (t & 3) * 4;
            int gr = row0 + r;
            float4 v = make_float4(0.f, 0.f, 0.f, 0.f);
            if (gr < N) v = *(const float4*)(A + (size_t)gr * HID + k0 + kk);
            As[kk + 0][r] = v.x; As[kk + 1][r] = v.y;
            As[kk + 2][r] = v.z; As[kk + 3][r] = v.w;
        }
        {
            int kk = t >> 4;
            int c4 = (t & 15) * 4;
            *(float4*)&Bs[kk][c4] = *(const float4*)(W + (size_t)(k0 + kk) * HID + col0 + c4);
        }
        __syncthreads();
        #pragma unroll
        for (int k = 0; k < KC; k++) {
            float4 a = *(const float4*)&As[k][tr * 4];
            float4 b = *(const float4*)&Bs[k][tc * 4];
            float av[4] = {a.x, a.y, a.z, a.w};
            float bv[4] = {b.x, b.y, b.z, b.w};
            #pragma unroll
            for (int i = 0; i < 4; i++)
                #pragma unroll
                for (int j = 0; j < 4; j++)
                    acc[i][j] = fmaf(av[i], bv[j], acc[i][j]);
        }
        __syncthreads();
    }
    #pragma unroll
    for (int i = 0; i < 4; i++) {
        int gr = row0 + tr * 4 + i;
        if (gr < N) {
            __half2* dst = (__half2*)(C + (size_t)gr * HID + col0 + tc * 4);
            dst[0] = __float22half2_rn(make_float2(acc[i][0], acc[i][1]));
            dst[1] = __float22half2_rn(make_float2(acc[i][2], acc[i][3]));
        }
    }
}

// ---------------- aggregation ----------------
// out[n] = relu(sum_e w_e*T[src_e] + dis[n]^2*T[n] + b), T in fp16.
// Wave = 4 quarter-groups of 16 lanes; quarter q handles edge e+q; lane
// owns 8 features (one float4 = 8 halves). Partials combined via shfl_xor.

__device__ __forceinline__ void acc8(float* acc, float4 r, float w) {
    __half2* h = (__half2*)&r;
    #pragma unroll
    for (int k = 0; k < 4; k++) {
        float2 v = __half22float2(h[k]);
        acc[2 * k]     = fmaf(w, v.x, acc[2 * k]);
        acc[2 * k + 1] = fmaf(w, v.y, acc[2 * k + 1]);
    }
}

__global__ __launch_bounds__(256) void k_agg(const __half* __restrict__ T,
                                             const float* __restrict__ dis,
                                             const int* __restrict__ rowptr,
                                             const int* __restrict__ csr_src,
                                             const float* __restrict__ csr_w,
                                             const float* __restrict__ bias,
                                             float* __restrict__ out, int N) {
    const int wid  = threadIdx.x >> 6;
    const int lane = threadIdx.x & 63;
    const int q    = lane >> 4;      // quarter 0..3
    const int f    = lane & 15;      // float4 slot within row
    const int n = blockIdx.x * 4 + wid;
    if (n >= N) return;

    const float4* T4 = (const float4*)T;   // row = 16 float4s

    float acc[8] = {};

    int e  = rowptr[n];
    int e1 = rowptr[n + 1];
    for (; e + 8 <= e1; e += 8) {
        int   sA = csr_src[e + q];
        float wA = csr_w[e + q];
        int   sB = csr_src[e + 4 + q];
        float wB = csr_w[e + 4 + q];
        float4 rA = T4[(size_t)sA * 16 + f];
        float4 rB = T4[(size_t)sB * 16 + f];
        acc8(acc, rA, wA);
        acc8(acc, rB, wB);
    }
    for (; e < e1; e += 4) {
        int eq = e + q;
        bool ok = eq < e1;
        int   s = ok ? csr_src[eq] : 0;
        float w = ok ? csr_w[eq] : 0.f;
        float4 r = T4[(size_t)s * 16 + f];
        acc8(acc, r, w);
    }

    // self-loop: add only in quarter 0 (pre-combine)
    {
        float d = dis[n];
        float wS = (q == 0) ? d * d : 0.f;
        float4 rn = T4[(size_t)n * 16 + f];
        acc8(acc, rn, wS);
    }

    // combine quarters: lanes {f, f+16, f+32, f+48} hold partials of the
    // same 8 features
    #pragma unroll
    for (int k = 0; k < 8; k++) {
        acc[k] += __shfl_xor(acc[k], 16, 64);
        acc[k] += __shfl_xor(acc[k], 32, 64);
    }

    // lane (q,f) writes features 8f+2q, 8f+2q+1
    float2 b = ((const float2*)bias)[4 * f + q];
    float2 o;
    o.x = fmaxf(acc[2 * q]     + b.x, 0.f);
    o.y = fmaxf(acc[2 * q + 1] + b.y, 0.f);
    ((float2*)(out + (size_t)n * HID))[4 * f + q] = o;
}

// ---------------- pooling ----------------

__global__ void k_gstart(const int* __restrict__ batch, int* __restrict__ gstart, int N) {
    int g = blockIdx.x * blockDim.x + threadIdx.x;
    if (g > NGR) return;
    int lo = 0, hi = N;
    while (lo < hi) {
        int mid = (lo + hi) >> 1;
        if (batch[mid] < g) lo = mid + 1; else hi = mid;
    }
    gstart[g] = lo;
}

__global__ __launch_bounds__(128) void k_pool(const float* __restrict__ h,
                                              const int* __restrict__ gstart,
                                              float* __restrict__ g) {
    int gr = blockIdx.x;
    int f  = threadIdx.x;
    int s = gstart[gr], e = gstart[gr + 1];
    float acc = 0.f;
    for (int r = s; r < e; r++) acc += h[(size_t)r * HID + f];
    g[gr * HID + f] = acc / fmaxf((float)(e - s), 1.f);
}

// ---------------- MLP head ----------------

__global__ __launch_bounds__(128) void k_mlp(const float* __restrict__ g,
                                             const float* __restrict__ Wm0,
                                             const float* __restrict__ bm0,
                                             const float* __restrict__ Wm1,
                                             const float* __restrict__ bm1,
                                             float* __restrict__ out) {
    __shared__ float gl[HID];
    __shared__ float red[HID];
    int gr = blockIdx.x, j = threadIdx.x;
    gl[j] = g[gr * HID + j];
    __syncthreads();
    float acc = bm0[j];
    for (int k = 0; k < HID; k++) acc = fmaf(gl[k], Wm0[k * HID + j], acc);
    acc = fmaxf(acc, 0.f);
    red[j] = acc * Wm1[j];
    __syncthreads();
    for (int off = 64; off > 0; off >>= 1) {
        if (j < off) red[j] += red[j + off];
        __syncthreads();
    }
    if (j == 0) out[gr] = red[0] + bm1[0];
}

// ---------------- launch ----------------

extern "C" void kernel_launch(void* const* d_in, const int* in_sizes, int n_in,
                              void* d_out, int out_size, void* d_ws, size_t ws_size,
                              hipStream_t stream) {
    const float* x     = (const float*)d_in[0];
    const int*   ei    = (const int*)d_in[1];
    const int*   batch = (const int*)d_in[3];
    const float* W0 = (const float*)d_in[4],  *b0 = (const float*)d_in[5];
    const float* W1 = (const float*)d_in[6],  *b1 = (const float*)d_in[7];
    const float* W2 = (const float*)d_in[8],  *b2 = (const float*)d_in[9];
    const float* Wm0 = (const float*)d_in[10], *bm0 = (const float*)d_in[11];
    const float* Wm1 = (const float*)d_in[12], *bm1 = (const float*)d_in[13];

    const int N = in_sizes[0] / HID;
    const int E = in_sizes[1] / 2;
    const int nb = (N + NB_W - 1) >> NB_SHIFT;
    const int* row  = ei;
    const int* colI = ei + E;

    char* w = (char*)d_ws;
    auto carve = [&](size_t bytes) {
        void* p = (void*)w;
        w += (bytes + 255) & ~(size_t)255;
        return p;
    };
    int*    ibuf    = (int*)   carve(512 * 4);
    int*    bbase   = (int*)   carve(257 * 4);
    float*  dis     = (float*) carve((size_t)N * 4);
    int*    rowptr  = (int*)   carve((size_t)(N + 1) * 4);
    uint2*  sorted  = (uint2*) carve((size_t)E * 8);
    uint2*  sorted2 = (uint2*) carve((size_t)E * 8);
    int*    csr_src = (int*)   carve((size_t)E * 4);
    float*  csr_w   = (float*) carve((size_t)E * 4);
    __half* bufT    = (__half*)carve((size_t)N * HID * 2);
    float*  bufA    = (float*) carve((size_t)N * HID * 4);
    float*  bufB    = (float*) carve((size_t)N * HID * 4);
    float*  gsum    = (float*) carve((size_t)NGR * HID * 4);
    int*    gstart  = (int*)   carve((size_t)(NGR + 1) * 4);

    int* ghist = ibuf;
    int* bcur  = ibuf + 256;

    hipMemsetAsync(ibuf, 0, 512 * 4, stream);
    k_hist   <<<512, 256, 0, stream>>>(colI, ghist, E, nb);
    k_bscan  <<<1, 256, 0, stream>>>(ghist, bbase, rowptr, N, E, nb);
    k_scatter<<<(E + EPB - 1) / EPB, 256, 0, stream>>>(row, colI, bbase, bcur, sorted, E);
    k_build  <<<nb, 256, 0, stream>>>(sorted, bbase, sorted2, rowptr, dis, N);
    k_weight <<<(E + 255) / 256, 256, 0, stream>>>(sorted2, dis, csr_src, csr_w, E);

    dim3 gg((N + BM - 1) / BM, HID / BN);
    dim3 ga((N + 3) / 4);

    k_gemm<<<gg, 256, 0, stream>>>(x,    W0, bufT, N);
    k_agg <<<ga, 256, 0, stream>>>(bufT, dis, rowptr, csr_src, csr_w, b0, bufA, N);
    k_gemm<<<gg, 256, 0, stream>>>(bufA, W1, bufT, N);
    k_agg <<<ga, 256, 0, stream>>>(bufT, dis, rowptr, csr_src, csr_w, b1, bufB, N);
    k_gemm<<<gg, 256, 0, stream>>>(bufB, W2, bufT, N);
    k_agg <<<ga, 256, 0, stream>>>(bufT, dis, rowptr, csr_src, csr_w, b2, bufA, N);

    k_gstart<<<3, 256, 0, stream>>>(batch, gstart, N);
    k_pool<<<NGR, 128, 0, stream>>>(bufA, gstart, gsum);
    k_mlp<<<NGR, 128, 0, stream>>>(gsum, Wm0, bm0, Wm1, bm1, (float*)d_out);
}

// Round 4
// 793.888 us; speedup vs baseline: 1.8213x; 1.0573x over previous
//
#include <hip/hip_runtime.h>
#include <hip/hip_fp16.h>

// GCNRegressor: 3x GCNConv(128->128) + mean-pool + 2-layer MLP head.
// dis[s] folded into GEMM epilogue (T' = dis*T, fp16) -> edge stream is
// csr_src only, agg inner loop is a pure fp16-row sum with f32 accumulate.
// h kept in fp16 end-to-end. Bucket-sort prep packed to 1 uint per edge.

#define HID 128
#define NGR 512
#define NB_SHIFT 9
#define NB_W 512
#define EPB 4096

// ---------------- graph prep: bucket sort by destination ----------------

__global__ __launch_bounds__(256) void k_hist(const int* __restrict__ col,
                                              int* __restrict__ ghist, int E, int nb) {
    __shared__ int h[256];
    h[threadIdx.x] = 0;
    __syncthreads();
    for (int e = blockIdx.x * 256 + threadIdx.x; e < E; e += gridDim.x * 256)
        atomicAdd(&h[col[e] >> NB_SHIFT], 1);
    __syncthreads();
    int t = threadIdx.x;
    if (t < nb && h[t]) atomicAdd(&ghist[t], h[t]);
}

__global__ __launch_bounds__(256) void k_bscan(const int* __restrict__ ghist,
                                               int* __restrict__ bbase,
                                               int* __restrict__ rowptr,
                                               int N, int E, int nb) {
    __shared__ int wsum[4];
    int t = threadIdx.x, lane = t & 63, wid = t >> 6;
    int v = (t < nb) ? ghist[t] : 0;
    int sc = v;
    #pragma unroll
    for (int off = 1; off < 64; off <<= 1) {
        int u = __shfl_up(sc, off);
        if (lane >= off) sc += u;
    }
    if (lane == 63) wsum[wid] = sc;
    __syncthreads();
    int offs = 0;
    for (int w = 0; w < wid; w++) offs += wsum[w];
    int excl = offs + sc - v;
    if (t <= nb) bbase[t] = excl;
    if (t == 0) rowptr[N] = E;
}

// packed entry: (src << 9) | (dst & 511)
__global__ __launch_bounds__(256) void k_scatter(const int* __restrict__ row,
                                                 const int* __restrict__ col,
                                                 const int* __restrict__ bbase,
                                                 int* __restrict__ bcur,
                                                 unsigned* __restrict__ sorted, int E) {
    __shared__ int hist[256];
    __shared__ int cur[256];
    int t = threadIdx.x;
    hist[t] = 0;
    __syncthreads();
    int base = blockIdx.x * EPB;
    #pragma unroll
    for (int i = 0; i < EPB / 256; i++) {
        int e = base + i * 256 + t;
        if (e < E) atomicAdd(&hist[col[e] >> NB_SHIFT], 1);
    }
    __syncthreads();
    if (hist[t] > 0) cur[t] = atomicAdd(&bcur[t], hist[t]);
    __syncthreads();
    #pragma unroll
    for (int i = 0; i < EPB / 256; i++) {
        int e = base + i * 256 + t;
        if (e < E) {
            int d = col[e], b = d >> NB_SHIFT;
            int p = atomicAdd(&cur[b], 1);
            sorted[bbase[b] + p] = ((unsigned)row[e] << NB_SHIFT) | (unsigned)(d & (NB_W - 1));
        }
    }
}

// One block per bucket: histogram -> scan -> rowptr, dis, csr_src (in-bucket order).
__global__ __launch_bounds__(256) void k_build(const unsigned* __restrict__ sorted,
                                               const int* __restrict__ bbase,
                                               int* __restrict__ csr_src,
                                               int* __restrict__ rowptr,
                                               float* __restrict__ dis, int N) {
    __shared__ int cnt[NB_W];
    __shared__ int excl[NB_W];
    __shared__ int wsum[4];
    int b = blockIdx.x, t = threadIdx.x;
    cnt[t] = 0; cnt[t + 256] = 0;
    __syncthreads();
    int s0 = bbase[b], s1 = bbase[b + 1];
    for (int p = s0 + t; p < s1; p += 256)
        atomicAdd(&cnt[sorted[p] & (NB_W - 1)], 1);
    __syncthreads();
    int c0 = cnt[2 * t], c1 = cnt[2 * t + 1];
    int v = c0 + c1, lane = t & 63, wid = t >> 6;
    int sc = v;
    #pragma unroll
    for (int off = 1; off < 64; off <<= 1) {
        int u = __shfl_up(sc, off);
        if (lane >= off) sc += u;
    }
    if (lane == 63) wsum[wid] = sc;
    __syncthreads();
    int offs = 0;
    for (int w = 0; w < wid; w++) offs += wsum[w];
    int e0 = offs + sc - v;
    excl[2 * t] = e0;
    excl[2 * t + 1] = e0 + c0;
    int dbase = b << NB_SHIFT;
    int d0 = dbase + 2 * t, d1 = d0 + 1;
    if (d0 < N) { rowptr[d0] = s0 + e0;      dis[d0] = rsqrtf((float)(c0 + 1)); }
    if (d1 < N) { rowptr[d1] = s0 + e0 + c0; dis[d1] = rsqrtf((float)(c1 + 1)); }
    __syncthreads();
    for (int p = s0 + t; p < s1; p += 256) {
        unsigned sd = sorted[p];
        int q = atomicAdd(&excl[sd & (NB_W - 1)], 1);
        csr_src[s0 + q] = (int)(sd >> NB_SHIFT);
    }
}

// ---------------- GEMM: T'[N,128] (fp16) = dis[row] * (A[N,128] @ W[128,128]) ----

#define BM 64
#define BN 64
#define KC 16

__device__ __forceinline__ float4 load4(const float* p) { return *(const float4*)p; }
__device__ __forceinline__ float4 load4(const __half* p) {
    __half2 a = ((const __half2*)p)[0], b = ((const __half2*)p)[1];
    float2 x = __half22float2(a), y = __half22float2(b);
    return make_float4(x.x, x.y, y.x, y.y);
}

template <typename AT>
__global__ __launch_bounds__(256) void k_gemm(const AT* __restrict__ A,
                                              const float* __restrict__ W,
                                              const float* __restrict__ dis,
                                              __half* __restrict__ C, int N) {
    __shared__ float As[KC][BM];
    __shared__ float Bs[KC][BN];
    const int row0 = blockIdx.x * BM;
    const int col0 = blockIdx.y * BN;
    const int t  = threadIdx.x;
    const int tc = t & 15;
    const int tr = t >> 4;

    float acc[4][4] = {};

    for (int k0 = 0; k0 < HID; k0 += KC) {
        {
            int r  = t >> 2;
            int kk = (t & 3) * 4;
            int gr = row0 + r;
            float4 v = make_float4(0.f, 0.f, 0.f, 0.f);
            if (gr < N) v = load4(A + (size_t)gr * HID + k0 + kk);
            As[kk + 0][r] = v.x; As[kk + 1][r] = v.y;
            As[kk + 2][r] = v.z; As[kk + 3][r] = v.w;
        }
        {
            int kk = t >> 4;
            int c4 = (t & 15) * 4;
            *(float4*)&Bs[kk][c4] = *(const float4*)(W + (size_t)(k0 + kk) * HID + col0 + c4);
        }
        __syncthreads();
        #pragma unroll
        for (int k = 0; k < KC; k++) {
            float4 a = *(const float4*)&As[k][tr * 4];
            float4 b = *(const float4*)&Bs[k][tc * 4];
            float av[4] = {a.x, a.y, a.z, a.w};
            float bv[4] = {b.x, b.y, b.z, b.w};
            #pragma unroll
            for (int i = 0; i < 4; i++)
                #pragma unroll
                for (int j = 0; j < 4; j++)
                    acc[i][j] = fmaf(av[i], bv[j], acc[i][j]);
        }
        __syncthreads();
    }
    #pragma unroll
    for (int i = 0; i < 4; i++) {
        int gr = row0 + tr * 4 + i;
        if (gr < N) {
            float ds = dis[gr];
            __half2* dst = (__half2*)(C + (size_t)gr * HID + col0 + tc * 4);
            dst[0] = __float22half2_rn(make_float2(ds * acc[i][0], ds * acc[i][1]));
            dst[1] = __float22half2_rn(make_float2(ds * acc[i][2], ds * acc[i][3]));
        }
    }
}

// ---------------- aggregation ----------------
// out[n] = relu(dis[n] * (sum_e T'[src_e] + T'[n]) + b), T' fp16, f32 acc.
// Wave = 4 quarters of 16 lanes; quarter q covers edge e+q; lane owns 8
// features (one float4 = 8 halves); partials combined via shfl_xor.

__device__ __forceinline__ void add8(float* acc, float4 r) {
    __half2* h = (__half2*)&r;
    #pragma unroll
    for (int k = 0; k < 4; k++) {
        float2 v = __half22float2(h[k]);
        acc[2 * k]     += v.x;
        acc[2 * k + 1] += v.y;
    }
}

__global__ __launch_bounds__(256) void k_agg(const __half* __restrict__ T,
                                             const float* __restrict__ dis,
                                             const int* __restrict__ rowptr,
                                             const int* __restrict__ csr_src,
                                             const float* __restrict__ bias,
                                             __half* __restrict__ out, int N) {
    const int wid  = threadIdx.x >> 6;
    const int lane = threadIdx.x & 63;
    const int q    = lane >> 4;
    const int f    = lane & 15;
    const int n = blockIdx.x * 4 + wid;
    if (n >= N) return;

    const float4* T4 = (const float4*)T;   // row = 16 float4s (256 B)

    float acc[8] = {};

    int e  = rowptr[n];
    int e1 = rowptr[n + 1];
    for (; e + 16 <= e1; e += 16) {
        int s0 = csr_src[e + q];
        int s1 = csr_src[e + 4 + q];
        int s2 = csr_src[e + 8 + q];
        int s3 = csr_src[e + 12 + q];
        float4 r0 = T4[(size_t)s0 * 16 + f];
        float4 r1 = T4[(size_t)s1 * 16 + f];
        float4 r2 = T4[(size_t)s2 * 16 + f];
        float4 r3 = T4[(size_t)s3 * 16 + f];
        add8(acc, r0); add8(acc, r1); add8(acc, r2); add8(acc, r3);
    }
    for (; e + 4 <= e1; e += 4) {
        int s = csr_src[e + q];
        add8(acc, T4[(size_t)s * 16 + f]);
    }
    {
        int eq = e + q;
        if (eq < e1) {
            int s = csr_src[eq];
            add8(acc, T4[(size_t)s * 16 + f]);
        }
    }
    // self-loop (quarter 0 only, pre-combine)
    if (q == 0) add8(acc, T4[(size_t)n * 16 + f]);

    #pragma unroll
    for (int k = 0; k < 8; k++) {
        acc[k] += __shfl_xor(acc[k], 16, 64);
        acc[k] += __shfl_xor(acc[k], 32, 64);
    }

    float dn = dis[n];
    float2 b = ((const float2*)bias)[4 * f + q];
    float2 o;
    o.x = fmaxf(fmaf(dn, acc[2 * q],     b.x), 0.f);
    o.y = fmaxf(fmaf(dn, acc[2 * q + 1], b.y), 0.f);
    ((__half2*)(out + (size_t)n * HID))[4 * f + q] = __float22half2_rn(o);
}

// ---------------- pooling ----------------

__global__ void k_gstart(const int* __restrict__ batch, int* __restrict__ gstart, int N) {
    int g = blockIdx.x * blockDim.x + threadIdx.x;
    if (g > NGR) return;
    int lo = 0, hi = N;
    while (lo < hi) {
        int mid = (lo + hi) >> 1;
        if (batch[mid] < g) lo = mid + 1; else hi = mid;
    }
    gstart[g] = lo;
}

__global__ __launch_bounds__(128) void k_pool(const __half* __restrict__ h,
                                              const int* __restrict__ gstart,
                                              float* __restrict__ g) {
    int gr = blockIdx.x;
    int f  = threadIdx.x;
    int s = gstart[gr], e = gstart[gr + 1];
    float acc = 0.f;
    for (int r = s; r < e; r++) acc += __half2float(h[(size_t)r * HID + f]);
    g[gr * HID + f] = acc / fmaxf((float)(e - s), 1.f);
}

// ---------------- MLP head ----------------

__global__ __launch_bounds__(128) void k_mlp(const float* __restrict__ g,
                                             const float* __restrict__ Wm0,
                                             const float* __restrict__ bm0,
                                             const float* __restrict__ Wm1,
                                             const float* __restrict__ bm1,
                                             float* __restrict__ out) {
    __shared__ float gl[HID];
    __shared__ float red[HID];
    int gr = blockIdx.x, j = threadIdx.x;
    gl[j] = g[gr * HID + j];
    __syncthreads();
    float acc = bm0[j];
    for (int k = 0; k < HID; k++) acc = fmaf(gl[k], Wm0[k * HID + j], acc);
    acc = fmaxf(acc, 0.f);
    red[j] = acc * Wm1[j];
    __syncthreads();
    for (int off = 64; off > 0; off >>= 1) {
        if (j < off) red[j] += red[j + off];
        __syncthreads();
    }
    if (j == 0) out[gr] = red[0] + bm1[0];
}

// ---------------- launch ----------------

extern "C" void kernel_launch(void* const* d_in, const int* in_sizes, int n_in,
                              void* d_out, int out_size, void* d_ws, size_t ws_size,
                              hipStream_t stream) {
    const float* x     = (const float*)d_in[0];
    const int*   ei    = (const int*)d_in[1];
    const int*   batch = (const int*)d_in[3];
    const float* W0 = (const float*)d_in[4],  *b0 = (const float*)d_in[5];
    const float* W1 = (const float*)d_in[6],  *b1 = (const float*)d_in[7];
    const float* W2 = (const float*)d_in[8],  *b2 = (const float*)d_in[9];
    const float* Wm0 = (const float*)d_in[10], *bm0 = (const float*)d_in[11];
    const float* Wm1 = (const float*)d_in[12], *bm1 = (const float*)d_in[13];

    const int N = in_sizes[0] / HID;
    const int E = in_sizes[1] / 2;
    const int nb = (N + NB_W - 1) >> NB_SHIFT;
    const int* row  = ei;
    const int* colI = ei + E;

    char* w = (char*)d_ws;
    auto carve = [&](size_t bytes) {
        void* p = (void*)w;
        w += (bytes + 255) & ~(size_t)255;
        return p;
    };
    int*      ibuf    = (int*)     carve(512 * 4);
    int*      bbase   = (int*)     carve(257 * 4);
    float*    dis     = (float*)   carve((size_t)N * 4);
    int*      rowptr  = (int*)     carve((size_t)(N + 1) * 4);
    unsigned* sorted  = (unsigned*)carve((size_t)E * 4);
    int*      csr_src = (int*)     carve((size_t)E * 4);
    __half*   bufT    = (__half*)  carve((size_t)N * HID * 2);
    __half*   bufA    = (__half*)  carve((size_t)N * HID * 2);
    __half*   bufB    = (__half*)  carve((size_t)N * HID * 2);
    float*    gsum    = (float*)   carve((size_t)NGR * HID * 4);
    int*      gstart  = (int*)     carve((size_t)(NGR + 1) * 4);

    int* ghist = ibuf;
    int* bcur  = ibuf + 256;

    hipMemsetAsync(ibuf, 0, 512 * 4, stream);
    k_hist   <<<512, 256, 0, stream>>>(colI, ghist, E, nb);
    k_bscan  <<<1, 256, 0, stream>>>(ghist, bbase, rowptr, N, E, nb);
    k_scatter<<<(E + EPB - 1) / EPB, 256, 0, stream>>>(row, colI, bbase, bcur, sorted, E);
    k_build  <<<nb, 256, 0, stream>>>(sorted, bbase, csr_src, rowptr, dis, N);

    dim3 gg((N + BM - 1) / BM, HID / BN);
    dim3 ga((N + 3) / 4);

    k_gemm<float> <<<gg, 256, 0, stream>>>(x,    W0, dis, bufT, N);
    k_agg         <<<ga, 256, 0, stream>>>(bufT, dis, rowptr, csr_src, b0, bufA, N);
    k_gemm<__half><<<gg, 256, 0, stream>>>(bufA, W1, dis, bufT, N);
    k_agg         <<<ga, 256, 0, stream>>>(bufT, dis, rowptr, csr_src, b1, bufB, N);
    k_gemm<__half><<<gg, 256, 0, stream>>>(bufB, W2, dis, bufT, N);
    k_agg         <<<ga, 256, 0, stream>>>(bufT, dis, rowptr, csr_src, b2, bufA, N);

    k_gstart<<<3, 256, 0, stream>>>(batch, gstart, N);
    k_pool<<<NGR, 128, 0, stream>>>(bufA, gstart, gsum);
    k_mlp<<<NGR, 128, 0, stream>>>(gsum, Wm0, bm0, Wm1, bm1, (float*)d_out);
}

// Round 5
// 773.152 us; speedup vs baseline: 1.8702x; 1.0268x over previous
//
#include <hip/hip_runtime.h>
#include <hip/hip_fp16.h>

// GCNRegressor: 3x GCNConv(128->128) + mean-pool + 2-layer MLP head.
// CSR-by-dst bucket sort; MFMA fp16 GEMM (f32 accum, register-only, W
// pre-transposed to fp16); dis folded into GEMM epilogue; fp16 h end-to-end;
// agg = pure fp16 row-sum gather with f32 accumulate.

#define HID 128
#define NGR 512
#define NB_SHIFT 9
#define NB_W 512
#define EPB 4096

typedef __attribute__((ext_vector_type(8))) _Float16 half8;
typedef __attribute__((ext_vector_type(4))) float floatx4;

// ---------------- graph prep: bucket sort by destination ----------------

__global__ __launch_bounds__(256) void k_hist(const int* __restrict__ col,
                                              int* __restrict__ ghist, int E, int nb) {
    __shared__ int h[256];
    h[threadIdx.x] = 0;
    __syncthreads();
    for (int e = blockIdx.x * 256 + threadIdx.x; e < E; e += gridDim.x * 256)
        atomicAdd(&h[col[e] >> NB_SHIFT], 1);
    __syncthreads();
    int t = threadIdx.x;
    if (t < nb && h[t]) atomicAdd(&ghist[t], h[t]);
}

__global__ __launch_bounds__(256) void k_bscan(const int* __restrict__ ghist,
                                               int* __restrict__ bbase,
                                               int* __restrict__ rowptr,
                                               int N, int E, int nb) {
    __shared__ int wsum[4];
    int t = threadIdx.x, lane = t & 63, wid = t >> 6;
    int v = (t < nb) ? ghist[t] : 0;
    int sc = v;
    #pragma unroll
    for (int off = 1; off < 64; off <<= 1) {
        int u = __shfl_up(sc, off);
        if (lane >= off) sc += u;
    }
    if (lane == 63) wsum[wid] = sc;
    __syncthreads();
    int offs = 0;
    for (int w = 0; w < wid; w++) offs += wsum[w];
    int excl = offs + sc - v;
    if (t <= nb) bbase[t] = excl;
    if (t == 0) rowptr[N] = E;
}

// packed entry: (src << 9) | (dst & 511)
__global__ __launch_bounds__(256) void k_scatter(const int* __restrict__ row,
                                                 const int* __restrict__ col,
                                                 const int* __restrict__ bbase,
                                                 int* __restrict__ bcur,
                                                 unsigned* __restrict__ sorted, int E) {
    __shared__ int hist[256];
    __shared__ int cur[256];
    int t = threadIdx.x;
    hist[t] = 0;
    __syncthreads();
    int base = blockIdx.x * EPB;
    #pragma unroll
    for (int i = 0; i < EPB / 256; i++) {
        int e = base + i * 256 + t;
        if (e < E) atomicAdd(&hist[col[e] >> NB_SHIFT], 1);
    }
    __syncthreads();
    if (hist[t] > 0) cur[t] = atomicAdd(&bcur[t], hist[t]);
    __syncthreads();
    #pragma unroll
    for (int i = 0; i < EPB / 256; i++) {
        int e = base + i * 256 + t;
        if (e < E) {
            int d = col[e], b = d >> NB_SHIFT;
            int p = atomicAdd(&cur[b], 1);
            sorted[bbase[b] + p] = ((unsigned)row[e] << NB_SHIFT) | (unsigned)(d & (NB_W - 1));
        }
    }
}

__global__ __launch_bounds__(256) void k_build(const unsigned* __restrict__ sorted,
                                               const int* __restrict__ bbase,
                                               int* __restrict__ csr_src,
                                               int* __restrict__ rowptr,
                                               float* __restrict__ dis, int N) {
    __shared__ int cnt[NB_W];
    __shared__ int excl[NB_W];
    __shared__ int wsum[4];
    int b = blockIdx.x, t = threadIdx.x;
    cnt[t] = 0; cnt[t + 256] = 0;
    __syncthreads();
    int s0 = bbase[b], s1 = bbase[b + 1];
    for (int p = s0 + t; p < s1; p += 256)
        atomicAdd(&cnt[sorted[p] & (NB_W - 1)], 1);
    __syncthreads();
    int c0 = cnt[2 * t], c1 = cnt[2 * t + 1];
    int v = c0 + c1, lane = t & 63, wid = t >> 6;
    int sc = v;
    #pragma unroll
    for (int off = 1; off < 64; off <<= 1) {
        int u = __shfl_up(sc, off);
        if (lane >= off) sc += u;
    }
    if (lane == 63) wsum[wid] = sc;
    __syncthreads();
    int offs = 0;
    for (int w = 0; w < wid; w++) offs += wsum[w];
    int e0 = offs + sc - v;
    excl[2 * t] = e0;
    excl[2 * t + 1] = e0 + c0;
    int dbase = b << NB_SHIFT;
    int d0 = dbase + 2 * t, d1 = d0 + 1;
    if (d0 < N) { rowptr[d0] = s0 + e0;      dis[d0] = rsqrtf((float)(c0 + 1)); }
    if (d1 < N) { rowptr[d1] = s0 + e0 + c0; dis[d1] = rsqrtf((float)(c1 + 1)); }
    __syncthreads();
    for (int p = s0 + t; p < s1; p += 256) {
        unsigned sd = sorted[p];
        int q = atomicAdd(&excl[sd & (NB_W - 1)], 1);
        csr_src[s0 + q] = (int)(sd >> NB_SHIFT);
    }
}

// ---------------- W prep: Wt[l][n][k] = (fp16) W_l[k][n] ----------------

__global__ __launch_bounds__(256) void k_wprep(const float* __restrict__ W0,
                                               const float* __restrict__ W1,
                                               const float* __restrict__ W2,
                                               _Float16* __restrict__ Wt) {
    int l = blockIdx.x >> 4;
    int chunk = blockIdx.x & 15;
    const float* W = (l == 0) ? W0 : (l == 1) ? W1 : W2;
    _Float16* D = Wt + (size_t)l * HID * HID;
    int t = threadIdx.x;
    int k  = chunk * 8 + (t >> 5);
    int n0 = (t & 31) * 4;
    float4 v = *(const float4*)(W + (size_t)k * HID + n0);
    D[(size_t)(n0 + 0) * HID + k] = (_Float16)v.x;
    D[(size_t)(n0 + 1) * HID + k] = (_Float16)v.y;
    D[(size_t)(n0 + 2) * HID + k] = (_Float16)v.z;
    D[(size_t)(n0 + 3) * HID + k] = (_Float16)v.w;
}

// ---------------- GEMM: T'[N,128] (fp16) = dis[row] * (A @ W) via MFMA ----
// Block = 4 waves, each wave a 16-row strip x full N=128, full K=128.
// A-frag: [m=lane&15][k=quad*8+j]; B-frag: [n=lane&15][k=quad*8+j] from
// pre-transposed Wt; C/D: col=lane&15, row=quad*4+reg (m89/m120 layouts).

__device__ __forceinline__ half8 load_a8(const _Float16* p) { return *(const half8*)p; }
__device__ __forceinline__ half8 load_a8(const float* p) {
    float4 v0 = *(const float4*)p;
    float4 v1 = *(const float4*)(p + 4);
    half8 h;
    h[0] = (_Float16)v0.x; h[1] = (_Float16)v0.y;
    h[2] = (_Float16)v0.z; h[3] = (_Float16)v0.w;
    h[4] = (_Float16)v1.x; h[5] = (_Float16)v1.y;
    h[6] = (_Float16)v1.z; h[7] = (_Float16)v1.w;
    return h;
}

template <typename AT>
__global__ __launch_bounds__(256) void k_gemm(const AT* __restrict__ A,
                                              const _Float16* __restrict__ Wt,
                                              const float* __restrict__ dis,
                                              __half* __restrict__ C, int N) {
    const int wv   = threadIdx.x >> 6;
    const int lane = threadIdx.x & 63;
    const int quad = lane >> 4;
    const int mc   = lane & 15;
    const int row0 = blockIdx.x * 64 + wv * 16;

    int arow = row0 + mc;
    if (arow >= N) arow = N - 1;          // clamp; stores are guarded

    floatx4 acc[8];
    #pragma unroll
    for (int j = 0; j < 8; j++) acc[j] = (floatx4){0.f, 0.f, 0.f, 0.f};

    #pragma unroll
    for (int s = 0; s < 4; s++) {
        const int k0 = s * 32 + quad * 8;
        half8 a = load_a8(A + (size_t)arow * HID + k0);
        #pragma unroll
        for (int j = 0; j < 8; j++) {
            half8 b = *(const half8*)(Wt + (size_t)(j * 16 + mc) * HID + k0);
            acc[j] = __builtin_amdgcn_mfma_f32_16x16x32_f16(a, b, acc[j], 0, 0, 0);
        }
    }

    int   gr[4];
    float ds[4];
    #pragma unroll
    for (int r = 0; r < 4; r++) {
        gr[r] = row0 + quad * 4 + r;
        ds[r] = (gr[r] < N) ? dis[gr[r]] : 0.f;
    }
    #pragma unroll
    for (int j = 0; j < 8; j++)
        #pragma unroll
        for (int r = 0; r < 4; r++)
            if (gr[r] < N)
                C[(size_t)gr[r] * HID + j * 16 + mc] = __float2half(ds[r] * acc[j][r]);
}

// ---------------- aggregation ----------------
// out[n] = relu(dis[n] * (sum_e T'[src_e] + T'[n]) + b), T' fp16, f32 acc.

__device__ __forceinline__ void add8(float* acc, float4 r) {
    __half2* h = (__half2*)&r;
    #pragma unroll
    for (int k = 0; k < 4; k++) {
        float2 v = __half22float2(h[k]);
        acc[2 * k]     += v.x;
        acc[2 * k + 1] += v.y;
    }
}

__global__ __launch_bounds__(256) void k_agg(const __half* __restrict__ T,
                                             const float* __restrict__ dis,
                                             const int* __restrict__ rowptr,
                                             const int* __restrict__ csr_src,
                                             const float* __restrict__ bias,
                                             __half* __restrict__ out, int N) {
    const int wid  = threadIdx.x >> 6;
    const int lane = threadIdx.x & 63;
    const int q    = lane >> 4;
    const int f    = lane & 15;
    const int n = blockIdx.x * 4 + wid;
    if (n >= N) return;

    const float4* T4 = (const float4*)T;   // row = 16 float4s (256 B)

    float acc[8] = {};

    int e  = rowptr[n];
    int e1 = rowptr[n + 1];
    for (; e + 16 <= e1; e += 16) {
        int s0 = csr_src[e + q];
        int s1 = csr_src[e + 4 + q];
        int s2 = csr_src[e + 8 + q];
        int s3 = csr_src[e + 12 + q];
        float4 r0 = T4[(size_t)s0 * 16 + f];
        float4 r1 = T4[(size_t)s1 * 16 + f];
        float4 r2 = T4[(size_t)s2 * 16 + f];
        float4 r3 = T4[(size_t)s3 * 16 + f];
        add8(acc, r0); add8(acc, r1); add8(acc, r2); add8(acc, r3);
    }
    for (; e + 4 <= e1; e += 4) {
        int s = csr_src[e + q];
        add8(acc, T4[(size_t)s * 16 + f]);
    }
    {
        int eq = e + q;
        if (eq < e1) {
            int s = csr_src[eq];
            add8(acc, T4[(size_t)s * 16 + f]);
        }
    }
    if (q == 0) add8(acc, T4[(size_t)n * 16 + f]);   // self-loop

    #pragma unroll
    for (int k = 0; k < 8; k++) {
        acc[k] += __shfl_xor(acc[k], 16, 64);
        acc[k] += __shfl_xor(acc[k], 32, 64);
    }

    float dn = dis[n];
    float2 b = ((const float2*)bias)[4 * f + q];
    float2 o;
    o.x = fmaxf(fmaf(dn, acc[2 * q],     b.x), 0.f);
    o.y = fmaxf(fmaf(dn, acc[2 * q + 1], b.y), 0.f);
    ((__half2*)(out + (size_t)n * HID))[4 * f + q] = __float22half2_rn(o);
}

// ---------------- pooling ----------------

__global__ void k_gstart(const int* __restrict__ batch, int* __restrict__ gstart, int N) {
    int g = blockIdx.x * blockDim.x + threadIdx.x;
    if (g > NGR) return;
    int lo = 0, hi = N;
    while (lo < hi) {
        int mid = (lo + hi) >> 1;
        if (batch[mid] < g) lo = mid + 1; else hi = mid;
    }
    gstart[g] = lo;
}

__global__ __launch_bounds__(128) void k_pool(const __half* __restrict__ h,
                                              const int* __restrict__ gstart,
                                              float* __restrict__ g) {
    int gr = blockIdx.x;
    int f  = threadIdx.x;
    int s = gstart[gr], e = gstart[gr + 1];
    float acc = 0.f;
    for (int r = s; r < e; r++) acc += __half2float(h[(size_t)r * HID + f]);
    g[gr * HID + f] = acc / fmaxf((float)(e - s), 1.f);
}

// ---------------- MLP head ----------------

__global__ __launch_bounds__(128) void k_mlp(const float* __restrict__ g,
                                             const float* __restrict__ Wm0,
                                             const float* __restrict__ bm0,
                                             const float* __restrict__ Wm1,
                                             const float* __restrict__ bm1,
                                             float* __restrict__ out) {
    __shared__ float gl[HID];
    __shared__ float red[HID];
    int gr = blockIdx.x, j = threadIdx.x;
    gl[j] = g[gr * HID + j];
    __syncthreads();
    float acc = bm0[j];
    for (int k = 0; k < HID; k++) acc = fmaf(gl[k], Wm0[k * HID + j], acc);
    acc = fmaxf(acc, 0.f);
    red[j] = acc * Wm1[j];
    __syncthreads();
    for (int off = 64; off > 0; off >>= 1) {
        if (j < off) red[j] += red[j + off];
        __syncthreads();
    }
    if (j == 0) out[gr] = red[0] + bm1[0];
}

// ---------------- launch ----------------

extern "C" void kernel_launch(void* const* d_in, const int* in_sizes, int n_in,
                              void* d_out, int out_size, void* d_ws, size_t ws_size,
                              hipStream_t stream) {
    const float* x     = (const float*)d_in[0];
    const int*   ei    = (const int*)d_in[1];
    const int*   batch = (const int*)d_in[3];
    const float* W0 = (const float*)d_in[4],  *b0 = (const float*)d_in[5];
    const float* W1 = (const float*)d_in[6],  *b1 = (const float*)d_in[7];
    const float* W2 = (const float*)d_in[8],  *b2 = (const float*)d_in[9];
    const float* Wm0 = (const float*)d_in[10], *bm0 = (const float*)d_in[11];
    const float* Wm1 = (const float*)d_in[12], *bm1 = (const float*)d_in[13];

    const int N = in_sizes[0] / HID;
    const int E = in_sizes[1] / 2;
    const int nb = (N + NB_W - 1) >> NB_SHIFT;
    const int* row  = ei;
    const int* colI = ei + E;

    char* w = (char*)d_ws;
    auto carve = [&](size_t bytes) {
        void* p = (void*)w;
        w += (bytes + 255) & ~(size_t)255;
        return p;
    };
    int*      ibuf    = (int*)     carve(512 * 4);
    int*      bbase   = (int*)     carve(257 * 4);
    float*    dis     = (float*)   carve((size_t)N * 4);
    int*      rowptr  = (int*)     carve((size_t)(N + 1) * 4);
    unsigned* sorted  = (unsigned*)carve((size_t)E * 4);
    int*      csr_src = (int*)     carve((size_t)E * 4);
    _Float16* wth     = (_Float16*)carve((size_t)3 * HID * HID * 2);
    __half*   bufT    = (__half*)  carve((size_t)N * HID * 2);
    __half*   bufA    = (__half*)  carve((size_t)N * HID * 2);
    __half*   bufB    = (__half*)  carve((size_t)N * HID * 2);
    float*    gsum    = (float*)   carve((size_t)NGR * HID * 4);
    int*      gstart  = (int*)     carve((size_t)(NGR + 1) * 4);

    int* ghist = ibuf;
    int* bcur  = ibuf + 256;

    hipMemsetAsync(ibuf, 0, 512 * 4, stream);
    k_wprep  <<<48, 256, 0, stream>>>(W0, W1, W2, wth);
    k_hist   <<<512, 256, 0, stream>>>(colI, ghist, E, nb);
    k_bscan  <<<1, 256, 0, stream>>>(ghist, bbase, rowptr, N, E, nb);
    k_scatter<<<(E + EPB - 1) / EPB, 256, 0, stream>>>(row, colI, bbase, bcur, sorted, E);
    k_build  <<<nb, 256, 0, stream>>>(sorted, bbase, csr_src, rowptr, dis, N);

    dim3 gg((N + 63) / 64);
    dim3 ga((N + 3) / 4);

    k_gemm<float>    <<<gg, 256, 0, stream>>>(x, wth, dis, bufT, N);
    k_agg            <<<ga, 256, 0, stream>>>(bufT, dis, rowptr, csr_src, b0, bufA, N);
    k_gemm<_Float16> <<<gg, 256, 0, stream>>>((const _Float16*)bufA, wth + HID * HID, dis, bufT, N);
    k_agg            <<<ga, 256, 0, stream>>>(bufT, dis, rowptr, csr_src, b1, bufB, N);
    k_gemm<_Float16> <<<gg, 256, 0, stream>>>((const _Float16*)bufB, wth + 2 * HID * HID, dis, bufT, N);
    k_agg            <<<ga, 256, 0, stream>>>(bufT, dis, rowptr, csr_src, b2, bufA, N);

    k_gstart<<<3, 256, 0, stream>>>(batch, gstart, N);
    k_pool<<<NGR, 128, 0, stream>>>(bufA, gstart, gsum);
    k_mlp<<<NGR, 128, 0, stream>>>(gsum, Wm0, bm0, Wm1, bm1, (float*)d_out);
}

// Round 6
// 699.933 us; speedup vs baseline: 2.0658x; 1.1046x over previous
//
#include <hip/hip_runtime.h>
#include <hip/hip_fp16.h>

// GCNRegressor: 3x GCNConv(128->128) + mean-pool + 2-layer MLP head.
// CSR-by-dst bucket sort; MFMA fp16 GEMM with register-resident B (loaded
// once per wave, grid-stride strips); T stored in TWO 64-feature slices
// (12.8 MB each) and aggregated in 2 passes so the random-gather working
// set per pass halves (per-XCD L2 capacity misses shrink); fp16 h
// end-to-end in the same 2-slice layout; f32 accumulate everywhere.

#define HID 128
#define NGR 512
#define NB_SHIFT 9
#define NB_W 512
#define EPB 4096

typedef __attribute__((ext_vector_type(8))) _Float16 half8;
typedef __attribute__((ext_vector_type(4))) float floatx4;

// ---------------- graph prep: bucket sort by destination ----------------

__global__ __launch_bounds__(256) void k_hist(const int* __restrict__ col,
                                              int* __restrict__ ghist, int E, int nb) {
    __shared__ int h[256];
    h[threadIdx.x] = 0;
    __syncthreads();
    for (int e = blockIdx.x * 256 + threadIdx.x; e < E; e += gridDim.x * 256)
        atomicAdd(&h[col[e] >> NB_SHIFT], 1);
    __syncthreads();
    int t = threadIdx.x;
    if (t < nb && h[t]) atomicAdd(&ghist[t], h[t]);
}

__global__ __launch_bounds__(256) void k_bscan(const int* __restrict__ ghist,
                                               int* __restrict__ bbase,
                                               int* __restrict__ rowptr,
                                               int N, int E, int nb) {
    __shared__ int wsum[4];
    int t = threadIdx.x, lane = t & 63, wid = t >> 6;
    int v = (t < nb) ? ghist[t] : 0;
    int sc = v;
    #pragma unroll
    for (int off = 1; off < 64; off <<= 1) {
        int u = __shfl_up(sc, off);
        if (lane >= off) sc += u;
    }
    if (lane == 63) wsum[wid] = sc;
    __syncthreads();
    int offs = 0;
    for (int w = 0; w < wid; w++) offs += wsum[w];
    int excl = offs + sc - v;
    if (t <= nb) bbase[t] = excl;
    if (t == 0) rowptr[N] = E;
}

// packed entry: (src << 9) | (dst & 511)
__global__ __launch_bounds__(256) void k_scatter(const int* __restrict__ row,
                                                 const int* __restrict__ col,
                                                 const int* __restrict__ bbase,
                                                 int* __restrict__ bcur,
                                                 unsigned* __restrict__ sorted, int E) {
    __shared__ int hist[256];
    __shared__ int cur[256];
    int t = threadIdx.x;
    hist[t] = 0;
    __syncthreads();
    int base = blockIdx.x * EPB;
    #pragma unroll
    for (int i = 0; i < EPB / 256; i++) {
        int e = base + i * 256 + t;
        if (e < E) atomicAdd(&hist[col[e] >> NB_SHIFT], 1);
    }
    __syncthreads();
    if (hist[t] > 0) cur[t] = atomicAdd(&bcur[t], hist[t]);
    __syncthreads();
    #pragma unroll
    for (int i = 0; i < EPB / 256; i++) {
        int e = base + i * 256 + t;
        if (e < E) {
            int d = col[e], b = d >> NB_SHIFT;
            int p = atomicAdd(&cur[b], 1);
            sorted[bbase[b] + p] = ((unsigned)row[e] << NB_SHIFT) | (unsigned)(d & (NB_W - 1));
        }
    }
}

__global__ __launch_bounds__(256) void k_build(const unsigned* __restrict__ sorted,
                                               const int* __restrict__ bbase,
                                               int* __restrict__ csr_src,
                                               int* __restrict__ rowptr,
                                               float* __restrict__ dis, int N) {
    __shared__ int cnt[NB_W];
    __shared__ int excl[NB_W];
    __shared__ int wsum[4];
    int b = blockIdx.x, t = threadIdx.x;
    cnt[t] = 0; cnt[t + 256] = 0;
    __syncthreads();
    int s0 = bbase[b], s1 = bbase[b + 1];
    for (int p = s0 + t; p < s1; p += 256)
        atomicAdd(&cnt[sorted[p] & (NB_W - 1)], 1);
    __syncthreads();
    int c0 = cnt[2 * t], c1 = cnt[2 * t + 1];
    int v = c0 + c1, lane = t & 63, wid = t >> 6;
    int sc = v;
    #pragma unroll
    for (int off = 1; off < 64; off <<= 1) {
        int u = __shfl_up(sc, off);
        if (lane >= off) sc += u;
    }
    if (lane == 63) wsum[wid] = sc;
    __syncthreads();
    int offs = 0;
    for (int w = 0; w < wid; w++) offs += wsum[w];
    int e0 = offs + sc - v;
    excl[2 * t] = e0;
    excl[2 * t + 1] = e0 + c0;
    int dbase = b << NB_SHIFT;
    int d0 = dbase + 2 * t, d1 = d0 + 1;
    if (d0 < N) { rowptr[d0] = s0 + e0;      dis[d0] = rsqrtf((float)(c0 + 1)); }
    if (d1 < N) { rowptr[d1] = s0 + e0 + c0; dis[d1] = rsqrtf((float)(c1 + 1)); }
    __syncthreads();
    for (int p = s0 + t; p < s1; p += 256) {
        unsigned sd = sorted[p];
        int q = atomicAdd(&excl[sd & (NB_W - 1)], 1);
        csr_src[s0 + q] = (int)(sd >> NB_SHIFT);
    }
}

// ---------------- W prep: Wt[l][n][k] = (fp16) W_l[k][n] ----------------

__global__ __launch_bounds__(256) void k_wprep(const float* __restrict__ W0,
                                               const float* __restrict__ W1,
                                               const float* __restrict__ W2,
                                               _Float16* __restrict__ Wt) {
    int l = blockIdx.x >> 4;
    int chunk = blockIdx.x & 15;
    const float* W = (l == 0) ? W0 : (l == 1) ? W1 : W2;
    _Float16* D = Wt + (size_t)l * HID * HID;
    int t = threadIdx.x;
    int k  = chunk * 8 + (t >> 5);
    int n0 = (t & 31) * 4;
    float4 v = *(const float4*)(W + (size_t)k * HID + n0);
    D[(size_t)(n0 + 0) * HID + k] = (_Float16)v.x;
    D[(size_t)(n0 + 1) * HID + k] = (_Float16)v.y;
    D[(size_t)(n0 + 2) * HID + k] = (_Float16)v.z;
    D[(size_t)(n0 + 3) * HID + k] = (_Float16)v.w;
}

// ---------------- GEMM: T'(2-slice fp16) = dis[row] * (A @ W) via MFMA ----
// B (whole 128x128 Wt) lives in registers: 32 half8 frags loaded once per
// wave. Wave grid-strides over 16-row strips; A prefetched one strip ahead.
// C written in 2-slice layout: elem (r, c) at [(c>>6)*N + r]*64 + (c&63).

__device__ __forceinline__ half8 load_afrag(const float* A, int arow, int k0, int N) {
    const float* p = A + (size_t)arow * HID + k0;   // x: dense f32 row-major
    float4 v0 = *(const float4*)p;
    float4 v1 = *(const float4*)(p + 4);
    half8 h;
    h[0] = (_Float16)v0.x; h[1] = (_Float16)v0.y;
    h[2] = (_Float16)v0.z; h[3] = (_Float16)v0.w;
    h[4] = (_Float16)v1.x; h[5] = (_Float16)v1.y;
    h[6] = (_Float16)v1.z; h[7] = (_Float16)v1.w;
    return h;
}
__device__ __forceinline__ half8 load_afrag(const _Float16* A, int arow, int k0, int N) {
    // h: 2-slice layout
    return *(const half8*)(A + ((size_t)(k0 >> 6) * N + arow) * 64 + (k0 & 63));
}

template <typename AT>
__global__ __launch_bounds__(256, 2) void k_gemm(const AT* __restrict__ A,
                                                 const _Float16* __restrict__ Wt,
                                                 const float* __restrict__ dis,
                                                 __half* __restrict__ C, int N) {
    const int lane = threadIdx.x & 63;
    const int quad = lane >> 4;
    const int mc   = lane & 15;
    const int gw   = (blockIdx.x * 256 + threadIdx.x) >> 6;
    const int nw   = (gridDim.x * 256) >> 6;
    const int nstrips = (N + 15) >> 4;

    half8 b[8][4];
    #pragma unroll
    for (int j = 0; j < 8; j++)
        #pragma unroll
        for (int s = 0; s < 4; s++)
            b[j][s] = *(const half8*)(Wt + (size_t)(j * 16 + mc) * HID + s * 32 + quad * 8);

    int strip = gw;
    if (strip >= nstrips) return;

    half8 a[4];
    {
        int arow = strip * 16 + mc; if (arow >= N) arow = N - 1;
        #pragma unroll
        for (int s = 0; s < 4; s++) a[s] = load_afrag(A, arow, s * 32 + quad * 8, N);
    }

    for (; strip < nstrips; strip += nw) {
        const int row0 = strip * 16;
        const int next = strip + nw;
        half8 an[4];
        if (next < nstrips) {
            int arow = next * 16 + mc; if (arow >= N) arow = N - 1;
            #pragma unroll
            for (int s = 0; s < 4; s++) an[s] = load_afrag(A, arow, s * 32 + quad * 8, N);
        }
        floatx4 acc[8];
        #pragma unroll
        for (int j = 0; j < 8; j++) acc[j] = (floatx4){0.f, 0.f, 0.f, 0.f};
        #pragma unroll
        for (int s = 0; s < 4; s++)
            #pragma unroll
            for (int j = 0; j < 8; j++)
                acc[j] = __builtin_amdgcn_mfma_f32_16x16x32_f16(a[s], b[j][s], acc[j], 0, 0, 0);
        #pragma unroll
        for (int r = 0; r < 4; r++) {
            int gr = row0 + quad * 4 + r;
            if (gr < N) {
                float ds = dis[gr];
                #pragma unroll
                for (int j = 0; j < 8; j++)
                    C[((size_t)(j >> 2) * N + gr) * 64 + (j & 3) * 16 + mc] =
                        __float2half(ds * acc[j][r]);
            }
        }
        #pragma unroll
        for (int s = 0; s < 4; s++) a[s] = an[s];
    }
}

// ---------------- aggregation (2 feature-slice passes) ----------------
// pass = blockIdx.y selects the 64-feature slice (12.8 MB gather set).
// Half-wave (32 lanes) per dst: p = edge slot (4), h = float4 slot (8).
// out[n] = relu(dis[n] * (sum_e T'[src] + T'[n]) + b), f32 accumulate.

__device__ __forceinline__ void add8(float* acc, float4 r) {
    __half2* h = (__half2*)&r;
    #pragma unroll
    for (int k = 0; k < 4; k++) {
        float2 v = __half22float2(h[k]);
        acc[2 * k]     += v.x;
        acc[2 * k + 1] += v.y;
    }
}

__global__ __launch_bounds__(256) void k_agg(const __half* __restrict__ T,
                                             const float* __restrict__ dis,
                                             const int* __restrict__ rowptr,
                                             const int* __restrict__ csr_src,
                                             const float* __restrict__ bias,
                                             __half* __restrict__ out, int N) {
    const int pass = blockIdx.y;
    const int g    = threadIdx.x >> 5;      // half-wave group 0..7
    const int l    = threadIdx.x & 31;
    const int p    = l >> 3;                // edge slot 0..3
    const int h    = l & 7;                 // float4 slot 0..7 (128 B slice row)
    const int n = blockIdx.x * 8 + g;
    if (n >= N) return;

    const float4* T4 = (const float4*)(T + (size_t)pass * N * 64);

    float acc[8] = {};

    int e  = rowptr[n];
    int e1 = rowptr[n + 1];
    for (; e + 16 <= e1; e += 16) {
        int s0 = csr_src[e + p];
        int s1 = csr_src[e + 4 + p];
        int s2 = csr_src[e + 8 + p];
        int s3 = csr_src[e + 12 + p];
        float4 r0 = T4[(size_t)s0 * 8 + h];
        float4 r1 = T4[(size_t)s1 * 8 + h];
        float4 r2 = T4[(size_t)s2 * 8 + h];
        float4 r3 = T4[(size_t)s3 * 8 + h];
        add8(acc, r0); add8(acc, r1); add8(acc, r2); add8(acc, r3);
    }
    for (; e + 4 <= e1; e += 4) {
        int s = csr_src[e + p];
        add8(acc, T4[(size_t)s * 8 + h]);
    }
    if (e + p < e1) {
        int s = csr_src[e + p];
        add8(acc, T4[(size_t)s * 8 + h]);
    }
    if (p == 0) add8(acc, T4[(size_t)n * 8 + h]);   // self-loop

    #pragma unroll
    for (int k = 0; k < 8; k++) {
        acc[k] += __shfl_xor(acc[k], 8, 64);
        acc[k] += __shfl_xor(acc[k], 16, 64);
    }

    if (p == 0) {
        float dn = dis[n];
        half8 o;
        #pragma unroll
        for (int k = 0; k < 8; k++) {
            float v = fmaf(dn, acc[k], bias[pass * 64 + h * 8 + k]);
            o[k] = (_Float16)fmaxf(v, 0.f);
        }
        *(half8*)((_Float16*)out + ((size_t)pass * N + n) * 64 + h * 8) = o;
    }
}

// ---------------- pooling (gstart fused: binary search per block) --------

__device__ __forceinline__ int lbound(const int* __restrict__ batch, int N, int g) {
    int lo = 0, hi = N;
    while (lo < hi) {
        int mid = (lo + hi) >> 1;
        if (batch[mid] < g) lo = mid + 1; else hi = mid;
    }
    return lo;
}

__global__ __launch_bounds__(128) void k_pool(const __half* __restrict__ h,
                                              const int* __restrict__ batch,
                                              float* __restrict__ g, int N) {
    int gr = blockIdx.x;
    int f  = threadIdx.x;
    int s = lbound(batch, N, gr), e = lbound(batch, N, gr + 1);
    const __half* hs = h + (size_t)(f >> 6) * N * 64;
    int c = f & 63;
    float acc = 0.f;
    for (int r = s; r < e; r++) acc += __half2float(hs[(size_t)r * 64 + c]);
    g[gr * HID + f] = acc / fmaxf((float)(e - s), 1.f);
}

// ---------------- MLP head ----------------

__global__ __launch_bounds__(128) void k_mlp(const float* __restrict__ g,
                                             const float* __restrict__ Wm0,
                                             const float* __restrict__ bm0,
                                             const float* __restrict__ Wm1,
                                             const float* __restrict__ bm1,
                                             float* __restrict__ out) {
    __shared__ float gl[HID];
    __shared__ float red[HID];
    int gr = blockIdx.x, j = threadIdx.x;
    gl[j] = g[gr * HID + j];
    __syncthreads();
    float acc = bm0[j];
    for (int k = 0; k < HID; k++) acc = fmaf(gl[k], Wm0[k * HID + j], acc);
    acc = fmaxf(acc, 0.f);
    red[j] = acc * Wm1[j];
    __syncthreads();
    for (int off = 64; off > 0; off >>= 1) {
        if (j < off) red[j] += red[j + off];
        __syncthreads();
    }
    if (j == 0) out[gr] = red[0] + bm1[0];
}

// ---------------- launch ----------------

extern "C" void kernel_launch(void* const* d_in, const int* in_sizes, int n_in,
                              void* d_out, int out_size, void* d_ws, size_t ws_size,
                              hipStream_t stream) {
    const float* x     = (const float*)d_in[0];
    const int*   ei    = (const int*)d_in[1];
    const int*   batch = (const int*)d_in[3];
    const float* W0 = (const float*)d_in[4],  *b0 = (const float*)d_in[5];
    const float* W1 = (const float*)d_in[6],  *b1 = (const float*)d_in[7];
    const float* W2 = (const float*)d_in[8],  *b2 = (const float*)d_in[9];
    const float* Wm0 = (const float*)d_in[10], *bm0 = (const float*)d_in[11];
    const float* Wm1 = (const float*)d_in[12], *bm1 = (const float*)d_in[13];

    const int N = in_sizes[0] / HID;
    const int E = in_sizes[1] / 2;
    const int nb = (N + NB_W - 1) >> NB_SHIFT;
    const int* row  = ei;
    const int* colI = ei + E;

    char* w = (char*)d_ws;
    auto carve = [&](size_t bytes) {
        void* p = (void*)w;
        w += (bytes + 255) & ~(size_t)255;
        return p;
    };
    int*      ibuf    = (int*)     carve(512 * 4);
    int*      bbase   = (int*)     carve(257 * 4);
    float*    dis     = (float*)   carve((size_t)N * 4);
    int*      rowptr  = (int*)     carve((size_t)(N + 1) * 4);
    unsigned* sorted  = (unsigned*)carve((size_t)E * 4);
    int*      csr_src = (int*)     carve((size_t)E * 4);
    _Float16* wth     = (_Float16*)carve((size_t)3 * HID * HID * 2);
    __half*   bufT    = (__half*)  carve((size_t)N * HID * 2);
    __half*   bufA    = (__half*)  carve((size_t)N * HID * 2);
    __half*   bufB    = (__half*)  carve((size_t)N * HID * 2);
    float*    gsum    = (float*)   carve((size_t)NGR * HID * 4);

    int* ghist = ibuf;
    int* bcur  = ibuf + 256;

    hipMemsetAsync(ibuf, 0, 512 * 4, stream);
    k_wprep  <<<48, 256, 0, stream>>>(W0, W1, W2, wth);
    k_hist   <<<512, 256, 0, stream>>>(colI, ghist, E, nb);
    k_bscan  <<<1, 256, 0, stream>>>(ghist, bbase, rowptr, N, E, nb);
    k_scatter<<<(E + EPB - 1) / EPB, 256, 0, stream>>>(row, colI, bbase, bcur, sorted, E);
    k_build  <<<nb, 256, 0, stream>>>(sorted, bbase, csr_src, rowptr, dis, N);

    dim3 gg(512);
    dim3 ga((N + 7) / 8, 2);

    k_gemm<float>    <<<gg, 256, 0, stream>>>(x, wth, dis, bufT, N);
    k_agg            <<<ga, 256, 0, stream>>>(bufT, dis, rowptr, csr_src, b0, bufA, N);
    k_gemm<_Float16> <<<gg, 256, 0, stream>>>((const _Float16*)bufA, wth + HID * HID, dis, bufT, N);
    k_agg            <<<ga, 256, 0, stream>>>(bufT, dis, rowptr, csr_src, b1, bufB, N);
    k_gemm<_Float16> <<<gg, 256, 0, stream>>>((const _Float16*)bufB, wth + 2 * HID * HID, dis, bufT, N);
    k_agg            <<<ga, 256, 0, stream>>>(bufT, dis, rowptr, csr_src, b2, bufA, N);

    k_pool<<<NGR, 128, 0, stream>>>(bufA, batch, gsum, N);
    k_mlp<<<NGR, 128, 0, stream>>>(gsum, Wm0, bm0, Wm1, bm1, (float*)d_out);
}

// Round 7
// 674.865 us; speedup vs baseline: 2.1425x; 1.0371x over previous
//
#include <hip/hip_runtime.h>
#include <hip/hip_fp16.h>

// GCNRegressor: 3x GCNConv(128->128) + mean-pool + 2-layer MLP head.
// CSR-by-dst bucket sort (512-thread blocks); MFMA fp16 GEMM with
// register-resident B; T in two 64-feature slices, 2-pass gather agg
// (f32 accumulate, 32-edge unroll); fused mean-pool + MLP head.

#define HID 128
#define NGR 512
#define NB_SHIFT 9
#define NB_W 512
#define EPB 4096

typedef __attribute__((ext_vector_type(8))) _Float16 half8;
typedef __attribute__((ext_vector_type(4))) float floatx4;

// ---------------- graph prep: bucket sort by destination ----------------

__global__ __launch_bounds__(256) void k_hist(const int* __restrict__ col,
                                              int* __restrict__ ghist, int E, int nb) {
    __shared__ int h[256];
    h[threadIdx.x] = 0;
    __syncthreads();
    for (int e = blockIdx.x * 256 + threadIdx.x; e < E; e += gridDim.x * 256)
        atomicAdd(&h[col[e] >> NB_SHIFT], 1);
    __syncthreads();
    int t = threadIdx.x;
    if (t < nb && h[t]) atomicAdd(&ghist[t], h[t]);
}

__global__ __launch_bounds__(256) void k_bscan(const int* __restrict__ ghist,
                                               int* __restrict__ bbase,
                                               int* __restrict__ rowptr,
                                               int N, int E, int nb) {
    __shared__ int wsum[4];
    int t = threadIdx.x, lane = t & 63, wid = t >> 6;
    int v = (t < nb) ? ghist[t] : 0;
    int sc = v;
    #pragma unroll
    for (int off = 1; off < 64; off <<= 1) {
        int u = __shfl_up(sc, off);
        if (lane >= off) sc += u;
    }
    if (lane == 63) wsum[wid] = sc;
    __syncthreads();
    int offs = 0;
    for (int w = 0; w < wid; w++) offs += wsum[w];
    int excl = offs + sc - v;
    if (t <= nb) bbase[t] = excl;
    if (t == 0) rowptr[N] = E;
}

// packed entry: (src << 9) | (dst & 511)
__global__ __launch_bounds__(512) void k_scatter(const int* __restrict__ row,
                                                 const int* __restrict__ col,
                                                 const int* __restrict__ bbase,
                                                 int* __restrict__ bcur,
                                                 unsigned* __restrict__ sorted, int E) {
    __shared__ int hist[256];
    __shared__ int cur[256];
    int t = threadIdx.x;
    if (t < 256) hist[t] = 0;
    __syncthreads();
    int base = blockIdx.x * EPB;
    #pragma unroll
    for (int i = 0; i < EPB / 512; i++) {
        int e = base + i * 512 + t;
        if (e < E) atomicAdd(&hist[col[e] >> NB_SHIFT], 1);
    }
    __syncthreads();
    if (t < 256 && hist[t] > 0) cur[t] = atomicAdd(&bcur[t], hist[t]);
    __syncthreads();
    #pragma unroll
    for (int i = 0; i < EPB / 512; i++) {
        int e = base + i * 512 + t;
        if (e < E) {
            int d = col[e], b = d >> NB_SHIFT;
            int p = atomicAdd(&cur[b], 1);
            sorted[bbase[b] + p] = ((unsigned)row[e] << NB_SHIFT) | (unsigned)(d & (NB_W - 1));
        }
    }
}

// One 512-thread block per bucket: count -> scan -> rowptr/dis/csr_src.
__global__ __launch_bounds__(512) void k_build(const unsigned* __restrict__ sorted,
                                               const int* __restrict__ bbase,
                                               int* __restrict__ csr_src,
                                               int* __restrict__ rowptr,
                                               float* __restrict__ dis, int N) {
    __shared__ int cnt[NB_W];
    __shared__ int excl[NB_W];
    __shared__ int wsum[8];
    int b = blockIdx.x, t = threadIdx.x;
    cnt[t] = 0;
    __syncthreads();
    int s0 = bbase[b], s1 = bbase[b + 1];
    for (int p = s0 + t; p < s1; p += 512)
        atomicAdd(&cnt[sorted[p] & (NB_W - 1)], 1);
    __syncthreads();
    int v = cnt[t];
    int lane = t & 63, wid = t >> 6;
    int sc = v;
    #pragma unroll
    for (int off = 1; off < 64; off <<= 1) {
        int u = __shfl_up(sc, off);
        if (lane >= off) sc += u;
    }
    if (lane == 63) wsum[wid] = sc;
    __syncthreads();
    int offs = 0;
    for (int w = 0; w < wid; w++) offs += wsum[w];
    int e0 = offs + sc - v;
    excl[t] = e0;
    int d = (b << NB_SHIFT) + t;
    if (d < N) { rowptr[d] = s0 + e0; dis[d] = rsqrtf((float)(v + 1)); }
    __syncthreads();
    for (int p = s0 + t; p < s1; p += 512) {
        unsigned sd = sorted[p];
        int q = atomicAdd(&excl[sd & (NB_W - 1)], 1);
        csr_src[s0 + q] = (int)(sd >> NB_SHIFT);
    }
}

// ---------------- W prep: Wt[l][n][k] = (fp16) W_l[k][n] ----------------

__global__ __launch_bounds__(256) void k_wprep(const float* __restrict__ W0,
                                               const float* __restrict__ W1,
                                               const float* __restrict__ W2,
                                               _Float16* __restrict__ Wt) {
    int l = blockIdx.x >> 4;
    int chunk = blockIdx.x & 15;
    const float* W = (l == 0) ? W0 : (l == 1) ? W1 : W2;
    _Float16* D = Wt + (size_t)l * HID * HID;
    int t = threadIdx.x;
    int k  = chunk * 8 + (t >> 5);
    int n0 = (t & 31) * 4;
    float4 v = *(const float4*)(W + (size_t)k * HID + n0);
    D[(size_t)(n0 + 0) * HID + k] = (_Float16)v.x;
    D[(size_t)(n0 + 1) * HID + k] = (_Float16)v.y;
    D[(size_t)(n0 + 2) * HID + k] = (_Float16)v.z;
    D[(size_t)(n0 + 3) * HID + k] = (_Float16)v.w;
}

// ---------------- GEMM: T'(2-slice fp16) = dis[row] * (A @ W) via MFMA ----
// B (whole 128x128 Wt) register-resident; wave grid-strides 16-row strips.
// C 2-slice layout: elem (r, c) at [(c>>6)*N + r]*64 + (c&63).

__device__ __forceinline__ half8 load_afrag(const float* A, int arow, int k0, int N) {
    const float* p = A + (size_t)arow * HID + k0;
    float4 v0 = *(const float4*)p;
    float4 v1 = *(const float4*)(p + 4);
    half8 h;
    h[0] = (_Float16)v0.x; h[1] = (_Float16)v0.y;
    h[2] = (_Float16)v0.z; h[3] = (_Float16)v0.w;
    h[4] = (_Float16)v1.x; h[5] = (_Float16)v1.y;
    h[6] = (_Float16)v1.z; h[7] = (_Float16)v1.w;
    return h;
}
__device__ __forceinline__ half8 load_afrag(const _Float16* A, int arow, int k0, int N) {
    return *(const half8*)(A + ((size_t)(k0 >> 6) * N + arow) * 64 + (k0 & 63));
}

template <typename AT>
__global__ __launch_bounds__(256, 2) void k_gemm(const AT* __restrict__ A,
                                                 const _Float16* __restrict__ Wt,
                                                 const float* __restrict__ dis,
                                                 __half* __restrict__ C, int N) {
    const int lane = threadIdx.x & 63;
    const int quad = lane >> 4;
    const int mc   = lane & 15;
    const int gw   = (blockIdx.x * 256 + threadIdx.x) >> 6;
    const int nw   = (gridDim.x * 256) >> 6;
    const int nstrips = (N + 15) >> 4;

    half8 b[8][4];
    #pragma unroll
    for (int j = 0; j < 8; j++)
        #pragma unroll
        for (int s = 0; s < 4; s++)
            b[j][s] = *(const half8*)(Wt + (size_t)(j * 16 + mc) * HID + s * 32 + quad * 8);

    int strip = gw;
    if (strip >= nstrips) return;

    half8 a[4];
    {
        int arow = strip * 16 + mc; if (arow >= N) arow = N - 1;
        #pragma unroll
        for (int s = 0; s < 4; s++) a[s] = load_afrag(A, arow, s * 32 + quad * 8, N);
    }

    for (; strip < nstrips; strip += nw) {
        const int row0 = strip * 16;
        const int next = strip + nw;
        half8 an[4];
        if (next < nstrips) {
            int arow = next * 16 + mc; if (arow >= N) arow = N - 1;
            #pragma unroll
            for (int s = 0; s < 4; s++) an[s] = load_afrag(A, arow, s * 32 + quad * 8, N);
        }
        floatx4 acc[8];
        #pragma unroll
        for (int j = 0; j < 8; j++) acc[j] = (floatx4){0.f, 0.f, 0.f, 0.f};
        #pragma unroll
        for (int s = 0; s < 4; s++)
            #pragma unroll
            for (int j = 0; j < 8; j++)
                acc[j] = __builtin_amdgcn_mfma_f32_16x16x32_f16(a[s], b[j][s], acc[j], 0, 0, 0);
        #pragma unroll
        for (int r = 0; r < 4; r++) {
            int gr = row0 + quad * 4 + r;
            if (gr < N) {
                float ds = dis[gr];
                #pragma unroll
                for (int j = 0; j < 8; j++)
                    C[((size_t)(j >> 2) * N + gr) * 64 + (j & 3) * 16 + mc] =
                        __float2half(ds * acc[j][r]);
            }
        }
        #pragma unroll
        for (int s = 0; s < 4; s++) a[s] = an[s];
    }
}

// ---------------- aggregation (2 feature-slice passes) ----------------

__device__ __forceinline__ void add8(float* acc, float4 r) {
    __half2* h = (__half2*)&r;
    #pragma unroll
    for (int k = 0; k < 4; k++) {
        float2 v = __half22float2(h[k]);
        acc[2 * k]     += v.x;
        acc[2 * k + 1] += v.y;
    }
}

__global__ __launch_bounds__(256) void k_agg(const __half* __restrict__ T,
                                             const float* __restrict__ dis,
                                             const int* __restrict__ rowptr,
                                             const int* __restrict__ csr_src,
                                             const float* __restrict__ bias,
                                             __half* __restrict__ out, int N) {
    const int pass = blockIdx.y;
    const int g    = threadIdx.x >> 5;
    const int l    = threadIdx.x & 31;
    const int p    = l >> 3;
    const int h    = l & 7;
    const int n = blockIdx.x * 8 + g;
    if (n >= N) return;

    const float4* T4 = (const float4*)(T + (size_t)pass * N * 64);

    float acc[8] = {};

    int e  = rowptr[n];
    int e1 = rowptr[n + 1];
    for (; e + 32 <= e1; e += 32) {
        int s0 = csr_src[e + p];
        int s1 = csr_src[e + 4 + p];
        int s2 = csr_src[e + 8 + p];
        int s3 = csr_src[e + 12 + p];
        int s4 = csr_src[e + 16 + p];
        int s5 = csr_src[e + 20 + p];
        int s6 = csr_src[e + 24 + p];
        int s7 = csr_src[e + 28 + p];
        float4 r0 = T4[(size_t)s0 * 8 + h];
        float4 r1 = T4[(size_t)s1 * 8 + h];
        float4 r2 = T4[(size_t)s2 * 8 + h];
        float4 r3 = T4[(size_t)s3 * 8 + h];
        float4 r4 = T4[(size_t)s4 * 8 + h];
        float4 r5 = T4[(size_t)s5 * 8 + h];
        float4 r6 = T4[(size_t)s6 * 8 + h];
        float4 r7 = T4[(size_t)s7 * 8 + h];
        add8(acc, r0); add8(acc, r1); add8(acc, r2); add8(acc, r3);
        add8(acc, r4); add8(acc, r5); add8(acc, r6); add8(acc, r7);
    }
    for (; e + 16 <= e1; e += 16) {
        int s0 = csr_src[e + p];
        int s1 = csr_src[e + 4 + p];
        int s2 = csr_src[e + 8 + p];
        int s3 = csr_src[e + 12 + p];
        float4 r0 = T4[(size_t)s0 * 8 + h];
        float4 r1 = T4[(size_t)s1 * 8 + h];
        float4 r2 = T4[(size_t)s2 * 8 + h];
        float4 r3 = T4[(size_t)s3 * 8 + h];
        add8(acc, r0); add8(acc, r1); add8(acc, r2); add8(acc, r3);
    }
    for (; e + 4 <= e1; e += 4) {
        int s = csr_src[e + p];
        add8(acc, T4[(size_t)s * 8 + h]);
    }
    if (e + p < e1) {
        int s = csr_src[e + p];
        add8(acc, T4[(size_t)s * 8 + h]);
    }
    if (p == 0) add8(acc, T4[(size_t)n * 8 + h]);   // self-loop

    #pragma unroll
    for (int k = 0; k < 8; k++) {
        acc[k] += __shfl_xor(acc[k], 8, 64);
        acc[k] += __shfl_xor(acc[k], 16, 64);
    }

    if (p == 0) {
        float dn = dis[n];
        half8 o;
        #pragma unroll
        for (int k = 0; k < 8; k++) {
            float v = fmaf(dn, acc[k], bias[pass * 64 + h * 8 + k]);
            o[k] = (_Float16)fmaxf(v, 0.f);
        }
        *(half8*)((_Float16*)out + ((size_t)pass * N + n) * 64 + h * 8) = o;
    }
}

// ---------------- fused mean-pool + MLP head ----------------
// One 256-thread block per graph. Pool: 16 rows in flight x 16 lanes of
// half8 (full 2-slice row per 16 lanes). Then MLP from LDS.

__device__ __forceinline__ int lbound(const int* __restrict__ batch, int N, int g) {
    int lo = 0, hi = N;
    while (lo < hi) {
        int mid = (lo + hi) >> 1;
        if (batch[mid] < g) lo = mid + 1; else hi = mid;
    }
    return lo;
}

__global__ __launch_bounds__(256) void k_poolmlp(const __half* __restrict__ hbuf,
                                                 const int* __restrict__ batch,
                                                 const float* __restrict__ Wm0,
                                                 const float* __restrict__ bm0,
                                                 const float* __restrict__ Wm1,
                                                 const float* __restrict__ bm1,
                                                 float* __restrict__ out, int N) {
    __shared__ float red[2048];
    __shared__ float g[HID];
    const int gr = blockIdx.x, t = threadIdx.x;
    const int s = lbound(batch, N, gr), e = lbound(batch, N, gr + 1);

    // pool: rg = row group (16), cl = column lane (16); cl<8 -> slice0, else slice1
    const int rg = t >> 4, cl = t & 15;
    const _Float16* base = (const _Float16*)hbuf
        + (size_t)(cl >> 3) * N * 64 + (size_t)(cl & 7) * 8;
    float acc[8] = {};
    for (int r = s + rg; r < e; r += 16) {
        half8 v = *(const half8*)(base + (size_t)r * 64);
        #pragma unroll
        for (int k = 0; k < 8; k++) acc[k] += (float)v[k];
    }
    #pragma unroll
    for (int k = 0; k < 8; k++) red[t * 8 + k] = acc[k];
    __syncthreads();
    if (t < 128) {
        int cl2 = t >> 3, k = t & 7;
        float sm = 0.f;
        #pragma unroll
        for (int rg2 = 0; rg2 < 16; rg2++) sm += red[(rg2 * 16 + cl2) * 8 + k];
        int feat = (cl2 & 7) * 8 + k + ((cl2 >> 3) ? 64 : 0);
        g[feat] = sm / fmaxf((float)(e - s), 1.f);
    }
    __syncthreads();

    // mlp layer 1: j = t&127, k-half = t>>7
    const int j = t & 127, hh = t >> 7;
    float a = 0.f;
    for (int k = hh * 64; k < hh * 64 + 64; k++)
        a = fmaf(g[k], Wm0[(size_t)k * HID + j], a);
    red[hh * 128 + j] = a;
    __syncthreads();

    if (t < 128) {
        float h1 = fmaxf(bm0[j] + red[j] + red[128 + j], 0.f);
        float z = h1 * Wm1[j];
        #pragma unroll
        for (int off = 32; off > 0; off >>= 1) z += __shfl_xor(z, off, 64);
        if ((t & 63) == 0) red[1024 + (t >> 6)] = z;
    }
    __syncthreads();
    if (t == 0) out[gr] = red[1024] + red[1025] + bm1[0];
}

// ---------------- launch ----------------

extern "C" void kernel_launch(void* const* d_in, const int* in_sizes, int n_in,
                              void* d_out, int out_size, void* d_ws, size_t ws_size,
                              hipStream_t stream) {
    const float* x     = (const float*)d_in[0];
    const int*   ei    = (const int*)d_in[1];
    const int*   batch = (const int*)d_in[3];
    const float* W0 = (const float*)d_in[4],  *b0 = (const float*)d_in[5];
    const float* W1 = (const float*)d_in[6],  *b1 = (const float*)d_in[7];
    const float* W2 = (const float*)d_in[8],  *b2 = (const float*)d_in[9];
    const float* Wm0 = (const float*)d_in[10], *bm0 = (const float*)d_in[11];
    const float* Wm1 = (const float*)d_in[12], *bm1 = (const float*)d_in[13];

    const int N = in_sizes[0] / HID;
    const int E = in_sizes[1] / 2;
    const int nb = (N + NB_W - 1) >> NB_SHIFT;
    const int* row  = ei;
    const int* colI = ei + E;

    char* w = (char*)d_ws;
    auto carve = [&](size_t bytes) {
        void* p = (void*)w;
        w += (bytes + 255) & ~(size_t)255;
        return p;
    };
    int*      ibuf    = (int*)     carve(512 * 4);
    int*      bbase   = (int*)     carve(257 * 4);
    float*    dis     = (float*)   carve((size_t)N * 4);
    int*      rowptr  = (int*)     carve((size_t)(N + 1) * 4);
    unsigned* sorted  = (unsigned*)carve((size_t)E * 4);
    int*      csr_src = (int*)     carve((size_t)E * 4);
    _Float16* wth     = (_Float16*)carve((size_t)3 * HID * HID * 2);
    __half*   bufT    = (__half*)  carve((size_t)N * HID * 2);
    __half*   bufA    = (__half*)  carve((size_t)N * HID * 2);
    __half*   bufB    = (__half*)  carve((size_t)N * HID * 2);

    int* ghist = ibuf;
    int* bcur  = ibuf + 256;

    hipMemsetAsync(ibuf, 0, 512 * 4, stream);
    k_wprep  <<<48, 256, 0, stream>>>(W0, W1, W2, wth);
    k_hist   <<<512, 256, 0, stream>>>(colI, ghist, E, nb);
    k_bscan  <<<1, 256, 0, stream>>>(ghist, bbase, rowptr, N, E, nb);
    k_scatter<<<(E + EPB - 1) / EPB, 512, 0, stream>>>(row, colI, bbase, bcur, sorted, E);
    k_build  <<<nb, 512, 0, stream>>>(sorted, bbase, csr_src, rowptr, dis, N);

    dim3 gg(512);
    dim3 ga((N + 7) / 8, 2);

    k_gemm<float>    <<<gg, 256, 0, stream>>>(x, wth, dis, bufT, N);
    k_agg            <<<ga, 256, 0, stream>>>(bufT, dis, rowptr, csr_src, b0, bufA, N);
    k_gemm<_Float16> <<<gg, 256, 0, stream>>>((const _Float16*)bufA, wth + HID * HID, dis, bufT, N);
    k_agg            <<<ga, 256, 0, stream>>>(bufT, dis, rowptr, csr_src, b1, bufB, N);
    k_gemm<_Float16> <<<gg, 256, 0, stream>>>((const _Float16*)bufB, wth + 2 * HID * HID, dis, bufT, N);
    k_agg            <<<ga, 256, 0, stream>>>(bufT, dis, rowptr, csr_src, b2, bufA, N);

    k_poolmlp<<<NGR, 256, 0, stream>>>(bufA, batch, Wm0, bm0, Wm1, bm1, (float*)d_out, N);
}

// Round 8
// 629.608 us; speedup vs baseline: 2.2965x; 1.0719x over previous
//
#include <hip/hip_runtime.h>
#include <hip/hip_fp16.h>

// GCNRegressor: 3x GCNConv(128->128) + mean-pool + 2-layer MLP head.
// CSR-by-dst bucket sort; MFMA fp16 GEMM with register-resident B; T in
// two 64-feature slices; 2-pass gather agg with XCD-pass affinity
// (blockIdx%8<4 -> slice0, else slice1: each XCD's L2 caches one slice);
// fused mean-pool + MLP head. f32 accumulate everywhere.

#define HID 128
#define NGR 512
#define NB_SHIFT 9
#define NB_W 512
#define EPB 4096

typedef __attribute__((ext_vector_type(8))) _Float16 half8;
typedef __attribute__((ext_vector_type(4))) float floatx4;

// ---------------- graph prep: bucket sort by destination ----------------

__global__ __launch_bounds__(256) void k_hist(const int* __restrict__ col,
                                              int* __restrict__ ghist, int E, int nb) {
    __shared__ int h[256];
    h[threadIdx.x] = 0;
    __syncthreads();
    for (int e = blockIdx.x * 256 + threadIdx.x; e < E; e += gridDim.x * 256)
        atomicAdd(&h[col[e] >> NB_SHIFT], 1);
    __syncthreads();
    int t = threadIdx.x;
    if (t < nb && h[t]) atomicAdd(&ghist[t], h[t]);
}

__global__ __launch_bounds__(256) void k_bscan(const int* __restrict__ ghist,
                                               int* __restrict__ bbase,
                                               int* __restrict__ rowptr,
                                               int N, int E, int nb) {
    __shared__ int wsum[4];
    int t = threadIdx.x, lane = t & 63, wid = t >> 6;
    int v = (t < nb) ? ghist[t] : 0;
    int sc = v;
    #pragma unroll
    for (int off = 1; off < 64; off <<= 1) {
        int u = __shfl_up(sc, off);
        if (lane >= off) sc += u;
    }
    if (lane == 63) wsum[wid] = sc;
    __syncthreads();
    int offs = 0;
    for (int w = 0; w < wid; w++) offs += wsum[w];
    int excl = offs + sc - v;
    if (t <= nb) bbase[t] = excl;
    if (t == 0) rowptr[N] = E;
}

// packed entry: (src << 9) | (dst & 511)
__global__ __launch_bounds__(512) void k_scatter(const int* __restrict__ row,
                                                 const int* __restrict__ col,
                                                 const int* __restrict__ bbase,
                                                 int* __restrict__ bcur,
                                                 unsigned* __restrict__ sorted, int E) {
    __shared__ int hist[256];
    __shared__ int cur[256];
    int t = threadIdx.x;
    if (t < 256) hist[t] = 0;
    __syncthreads();
    int base = blockIdx.x * EPB;
    #pragma unroll
    for (int i = 0; i < EPB / 512; i++) {
        int e = base + i * 512 + t;
        if (e < E) atomicAdd(&hist[col[e] >> NB_SHIFT], 1);
    }
    __syncthreads();
    if (t < 256 && hist[t] > 0) cur[t] = atomicAdd(&bcur[t], hist[t]);
    __syncthreads();
    #pragma unroll
    for (int i = 0; i < EPB / 512; i++) {
        int e = base + i * 512 + t;
        if (e < E) {
            int d = col[e], b = d >> NB_SHIFT;
            int p = atomicAdd(&cur[b], 1);
            sorted[bbase[b] + p] = ((unsigned)row[e] << NB_SHIFT) | (unsigned)(d & (NB_W - 1));
        }
    }
}

// One 512-thread block per bucket: count -> scan -> rowptr/dis/csr_src.
__global__ __launch_bounds__(512) void k_build(const unsigned* __restrict__ sorted,
                                               const int* __restrict__ bbase,
                                               int* __restrict__ csr_src,
                                               int* __restrict__ rowptr,
                                               float* __restrict__ dis, int N) {
    __shared__ int cnt[NB_W];
    __shared__ int excl[NB_W];
    __shared__ int wsum[8];
    int b = blockIdx.x, t = threadIdx.x;
    cnt[t] = 0;
    __syncthreads();
    int s0 = bbase[b], s1 = bbase[b + 1];
    for (int p = s0 + t; p < s1; p += 512)
        atomicAdd(&cnt[sorted[p] & (NB_W - 1)], 1);
    __syncthreads();
    int v = cnt[t];
    int lane = t & 63, wid = t >> 6;
    int sc = v;
    #pragma unroll
    for (int off = 1; off < 64; off <<= 1) {
        int u = __shfl_up(sc, off);
        if (lane >= off) sc += u;
    }
    if (lane == 63) wsum[wid] = sc;
    __syncthreads();
    int offs = 0;
    for (int w = 0; w < wid; w++) offs += wsum[w];
    int e0 = offs + sc - v;
    excl[t] = e0;
    int d = (b << NB_SHIFT) + t;
    if (d < N) { rowptr[d] = s0 + e0; dis[d] = rsqrtf((float)(v + 1)); }
    __syncthreads();
    for (int p = s0 + t; p < s1; p += 512) {
        unsigned sd = sorted[p];
        int q = atomicAdd(&excl[sd & (NB_W - 1)], 1);
        csr_src[s0 + q] = (int)(sd >> NB_SHIFT);
    }
}

// ---------------- W prep: Wt[l][n][k] = (fp16) W_l[k][n] ----------------

__global__ __launch_bounds__(256) void k_wprep(const float* __restrict__ W0,
                                               const float* __restrict__ W1,
                                               const float* __restrict__ W2,
                                               _Float16* __restrict__ Wt) {
    int l = blockIdx.x >> 4;
    int chunk = blockIdx.x & 15;
    const float* W = (l == 0) ? W0 : (l == 1) ? W1 : W2;
    _Float16* D = Wt + (size_t)l * HID * HID;
    int t = threadIdx.x;
    int k  = chunk * 8 + (t >> 5);
    int n0 = (t & 31) * 4;
    float4 v = *(const float4*)(W + (size_t)k * HID + n0);
    D[(size_t)(n0 + 0) * HID + k] = (_Float16)v.x;
    D[(size_t)(n0 + 1) * HID + k] = (_Float16)v.y;
    D[(size_t)(n0 + 2) * HID + k] = (_Float16)v.z;
    D[(size_t)(n0 + 3) * HID + k] = (_Float16)v.w;
}

// ---------------- GEMM: T'(2-slice fp16) = dis[row] * (A @ W) via MFMA ----
// B (whole 128x128 Wt) register-resident; wave grid-strides 16-row strips.
// C 2-slice layout: elem (r, c) at [(c>>6)*N + r]*64 + (c&63).

__device__ __forceinline__ half8 load_afrag(const float* A, int arow, int k0, int N) {
    const float* p = A + (size_t)arow * HID + k0;
    float4 v0 = *(const float4*)p;
    float4 v1 = *(const float4*)(p + 4);
    half8 h;
    h[0] = (_Float16)v0.x; h[1] = (_Float16)v0.y;
    h[2] = (_Float16)v0.z; h[3] = (_Float16)v0.w;
    h[4] = (_Float16)v1.x; h[5] = (_Float16)v1.y;
    h[6] = (_Float16)v1.z; h[7] = (_Float16)v1.w;
    return h;
}
__device__ __forceinline__ half8 load_afrag(const _Float16* A, int arow, int k0, int N) {
    return *(const half8*)(A + ((size_t)(k0 >> 6) * N + arow) * 64 + (k0 & 63));
}

template <typename AT>
__global__ __launch_bounds__(256, 2) void k_gemm(const AT* __restrict__ A,
                                                 const _Float16* __restrict__ Wt,
                                                 const float* __restrict__ dis,
                                                 __half* __restrict__ C, int N) {
    const int lane = threadIdx.x & 63;
    const int quad = lane >> 4;
    const int mc   = lane & 15;
    const int gw   = (blockIdx.x * 256 + threadIdx.x) >> 6;
    const int nw   = (gridDim.x * 256) >> 6;
    const int nstrips = (N + 15) >> 4;

    half8 b[8][4];
    #pragma unroll
    for (int j = 0; j < 8; j++)
        #pragma unroll
        for (int s = 0; s < 4; s++)
            b[j][s] = *(const half8*)(Wt + (size_t)(j * 16 + mc) * HID + s * 32 + quad * 8);

    int strip = gw;
    if (strip >= nstrips) return;

    half8 a[4];
    {
        int arow = strip * 16 + mc; if (arow >= N) arow = N - 1;
        #pragma unroll
        for (int s = 0; s < 4; s++) a[s] = load_afrag(A, arow, s * 32 + quad * 8, N);
    }

    for (; strip < nstrips; strip += nw) {
        const int row0 = strip * 16;
        const int next = strip + nw;
        half8 an[4];
        if (next < nstrips) {
            int arow = next * 16 + mc; if (arow >= N) arow = N - 1;
            #pragma unroll
            for (int s = 0; s < 4; s++) an[s] = load_afrag(A, arow, s * 32 + quad * 8, N);
        }
        floatx4 acc[8];
        #pragma unroll
        for (int j = 0; j < 8; j++) acc[j] = (floatx4){0.f, 0.f, 0.f, 0.f};
        #pragma unroll
        for (int s = 0; s < 4; s++)
            #pragma unroll
            for (int j = 0; j < 8; j++)
                acc[j] = __builtin_amdgcn_mfma_f32_16x16x32_f16(a[s], b[j][s], acc[j], 0, 0, 0);
        #pragma unroll
        for (int r = 0; r < 4; r++) {
            int gr = row0 + quad * 4 + r;
            if (gr < N) {
                float ds = dis[gr];
                #pragma unroll
                for (int j = 0; j < 8; j++)
                    C[((size_t)(j >> 2) * N + gr) * 64 + (j & 3) * 16 + mc] =
                        __float2half(ds * acc[j][r]);
            }
        }
        #pragma unroll
        for (int s = 0; s < 4; s++) a[s] = an[s];
    }
}

// ---------------- aggregation (2 feature-slice passes, XCD affinity) ------
// Flat grid; pass = (blockIdx>>2)&1 so blockIdx%8 in {0..3} -> slice 0 and
// {4..7} -> slice 1: with round-robin block->XCD dispatch each XCD's L2
// caches only ONE 12.8 MB slice. Half-wave per dst: p = edge slot (4),
// h = float4 slot (8). 16-edge unroll (24 VGPR / high occupancy — the 32
// unroll cost an occupancy step and regressed, R7).

__device__ __forceinline__ void add8(float* acc, float4 r) {
    __half2* h = (__half2*)&r;
    #pragma unroll
    for (int k = 0; k < 4; k++) {
        float2 v = __half22float2(h[k]);
        acc[2 * k]     += v.x;
        acc[2 * k + 1] += v.y;
    }
}

__global__ __launch_bounds__(256) void k_agg(const __half* __restrict__ T,
                                             const float* __restrict__ dis,
                                             const int* __restrict__ rowptr,
                                             const int* __restrict__ csr_src,
                                             const float* __restrict__ bias,
                                             __half* __restrict__ out, int N) {
    const int b    = blockIdx.x;
    const int pass = (b >> 2) & 1;
    const int nbi  = ((b >> 3) << 2) | (b & 3);
    const int g    = threadIdx.x >> 5;
    const int l    = threadIdx.x & 31;
    const int p    = l >> 3;
    const int h    = l & 7;
    const int n = nbi * 8 + g;
    if (n >= N) return;

    const float4* T4 = (const float4*)(T + (size_t)pass * N * 64);

    float acc[8] = {};

    int e  = rowptr[n];
    int e1 = rowptr[n + 1];
    for (; e + 16 <= e1; e += 16) {
        int s0 = csr_src[e + p];
        int s1 = csr_src[e + 4 + p];
        int s2 = csr_src[e + 8 + p];
        int s3 = csr_src[e + 12 + p];
        float4 r0 = T4[(size_t)s0 * 8 + h];
        float4 r1 = T4[(size_t)s1 * 8 + h];
        float4 r2 = T4[(size_t)s2 * 8 + h];
        float4 r3 = T4[(size_t)s3 * 8 + h];
        add8(acc, r0); add8(acc, r1); add8(acc, r2); add8(acc, r3);
    }
    for (; e + 4 <= e1; e += 4) {
        int s = csr_src[e + p];
        add8(acc, T4[(size_t)s * 8 + h]);
    }
    if (e + p < e1) {
        int s = csr_src[e + p];
        add8(acc, T4[(size_t)s * 8 + h]);
    }
    if (p == 0) add8(acc, T4[(size_t)n * 8 + h]);   // self-loop

    #pragma unroll
    for (int k = 0; k < 8; k++) {
        acc[k] += __shfl_xor(acc[k], 8, 64);
        acc[k] += __shfl_xor(acc[k], 16, 64);
    }

    if (p == 0) {
        float dn = dis[n];
        half8 o;
        #pragma unroll
        for (int k = 0; k < 8; k++) {
            float v = fmaf(dn, acc[k], bias[pass * 64 + h * 8 + k]);
            o[k] = (_Float16)fmaxf(v, 0.f);
        }
        *(half8*)((_Float16*)out + ((size_t)pass * N + n) * 64 + h * 8) = o;
    }
}

// ---------------- fused mean-pool + MLP head ----------------

__device__ __forceinline__ int lbound(const int* __restrict__ batch, int N, int g) {
    int lo = 0, hi = N;
    while (lo < hi) {
        int mid = (lo + hi) >> 1;
        if (batch[mid] < g) lo = mid + 1; else hi = mid;
    }
    return lo;
}

__global__ __launch_bounds__(256) void k_poolmlp(const __half* __restrict__ hbuf,
                                                 const int* __restrict__ batch,
                                                 const float* __restrict__ Wm0,
                                                 const float* __restrict__ bm0,
                                                 const float* __restrict__ Wm1,
                                                 const float* __restrict__ bm1,
                                                 float* __restrict__ out, int N) {
    __shared__ float red[2048];
    __shared__ float g[HID];
    const int gr = blockIdx.x, t = threadIdx.x;
    const int s = lbound(batch, N, gr), e = lbound(batch, N, gr + 1);

    const int rg = t >> 4, cl = t & 15;
    const _Float16* base = (const _Float16*)hbuf
        + (size_t)(cl >> 3) * N * 64 + (size_t)(cl & 7) * 8;
    float acc[8] = {};
    for (int r = s + rg; r < e; r += 16) {
        half8 v = *(const half8*)(base + (size_t)r * 64);
        #pragma unroll
        for (int k = 0; k < 8; k++) acc[k] += (float)v[k];
    }
    #pragma unroll
    for (int k = 0; k < 8; k++) red[t * 8 + k] = acc[k];
    __syncthreads();
    if (t < 128) {
        int cl2 = t >> 3, k = t & 7;
        float sm = 0.f;
        #pragma unroll
        for (int rg2 = 0; rg2 < 16; rg2++) sm += red[(rg2 * 16 + cl2) * 8 + k];
        int feat = (cl2 & 7) * 8 + k + ((cl2 >> 3) ? 64 : 0);
        g[feat] = sm / fmaxf((float)(e - s), 1.f);
    }
    __syncthreads();

    const int j = t & 127, hh = t >> 7;
    float a = 0.f;
    for (int k = hh * 64; k < hh * 64 + 64; k++)
        a = fmaf(g[k], Wm0[(size_t)k * HID + j], a);
    red[hh * 128 + j] = a;
    __syncthreads();

    if (t < 128) {
        float h1 = fmaxf(bm0[j] + red[j] + red[128 + j], 0.f);
        float z = h1 * Wm1[j];
        #pragma unroll
        for (int off = 32; off > 0; off >>= 1) z += __shfl_xor(z, off, 64);
        if ((t & 63) == 0) red[1024 + (t >> 6)] = z;
    }
    __syncthreads();
    if (t == 0) out[gr] = red[1024] + red[1025] + bm1[0];
}

// ---------------- launch ----------------

extern "C" void kernel_launch(void* const* d_in, const int* in_sizes, int n_in,
                              void* d_out, int out_size, void* d_ws, size_t ws_size,
                              hipStream_t stream) {
    const float* x     = (const float*)d_in[0];
    const int*   ei    = (const int*)d_in[1];
    const int*   batch = (const int*)d_in[3];
    const float* W0 = (const float*)d_in[4],  *b0 = (const float*)d_in[5];
    const float* W1 = (const float*)d_in[6],  *b1 = (const float*)d_in[7];
    const float* W2 = (const float*)d_in[8],  *b2 = (const float*)d_in[9];
    const float* Wm0 = (const float*)d_in[10], *bm0 = (const float*)d_in[11];
    const float* Wm1 = (const float*)d_in[12], *bm1 = (const float*)d_in[13];

    const int N = in_sizes[0] / HID;
    const int E = in_sizes[1] / 2;
    const int nb = (N + NB_W - 1) >> NB_SHIFT;
    const int* row  = ei;
    const int* colI = ei + E;

    char* w = (char*)d_ws;
    auto carve = [&](size_t bytes) {
        void* p = (void*)w;
        w += (bytes + 255) & ~(size_t)255;
        return p;
    };
    int*      ibuf    = (int*)     carve(512 * 4);
    int*      bbase   = (int*)     carve(257 * 4);
    float*    dis     = (float*)   carve((size_t)N * 4);
    int*      rowptr  = (int*)     carve((size_t)(N + 1) * 4);
    unsigned* sorted  = (unsigned*)carve((size_t)E * 4);
    int*      csr_src = (int*)     carve((size_t)E * 4);
    _Float16* wth     = (_Float16*)carve((size_t)3 * HID * HID * 2);
    __half*   bufT    = (__half*)  carve((size_t)N * HID * 2);
    __half*   bufA    = (__half*)  carve((size_t)N * HID * 2);
    __half*   bufB    = (__half*)  carve((size_t)N * HID * 2);

    int* ghist = ibuf;
    int* bcur  = ibuf + 256;

    hipMemsetAsync(ibuf, 0, 512 * 4, stream);
    k_wprep  <<<48, 256, 0, stream>>>(W0, W1, W2, wth);
    k_hist   <<<512, 256, 0, stream>>>(colI, ghist, E, nb);
    k_bscan  <<<1, 256, 0, stream>>>(ghist, bbase, rowptr, N, E, nb);
    k_scatter<<<(E + EPB - 1) / EPB, 512, 0, stream>>>(row, colI, bbase, bcur, sorted, E);
    k_build  <<<nb, 512, 0, stream>>>(sorted, bbase, csr_src, rowptr, dis, N);

    dim3 gg(512);
    const int nblk4 = (((N + 7) / 8) + 3) & ~3;   // node-blocks, padded to x4
    dim3 ga(2 * nblk4);

    k_gemm<float>    <<<gg, 256, 0, stream>>>(x, wth, dis, bufT, N);
    k_agg            <<<ga, 256, 0, stream>>>(bufT, dis, rowptr, csr_src, b0, bufA, N);
    k_gemm<_Float16> <<<gg, 256, 0, stream>>>((const _Float16*)bufA, wth + HID * HID, dis, bufT, N);
    k_agg            <<<ga, 256, 0, stream>>>(bufT, dis, rowptr, csr_src, b1, bufB, N);
    k_gemm<_Float16> <<<gg, 256, 0, stream>>>((const _Float16*)bufB, wth + 2 * HID * HID, dis, bufT, N);
    k_agg            <<<ga, 256, 0, stream>>>(bufT, dis, rowptr, csr_src, b2, bufA, N);

    k_poolmlp<<<NGR, 256, 0, stream>>>(bufA, batch, Wm0, bm0, Wm1, bm1, (float*)d_out, N);
}